// Round 1
// 352.565 us; speedup vs baseline: 1.0759x; 1.0759x over previous
//
#include <hip/hip_runtime.h>
#include <cstdint>
#include <cstddef>

typedef _Float16 f16;
typedef _Float16 f16x8 __attribute__((ext_vector_type(8)));
typedef float f32x4 __attribute__((ext_vector_type(4)));

#define SEQ 1024

// ---------------------------------------------------------------------------
// helpers
// ---------------------------------------------------------------------------
__device__ __forceinline__ float wave_sum64(float v) {
#pragma unroll
  for (int m = 1; m < 64; m <<= 1) v += __shfl_xor(v, m);
  return v;
}

// ---------------------------------------------------------------------------
// fused: RMSNorm (blocks 0..2047) + attention-weight transpose (blocks 2048+)
// transpose: f32 [K,N] -> f16 [N,K], 64x64 tiles (wq/wk/wv/wo only).
// ---------------------------------------------------------------------------
struct TJobs4 {
  const float* src[4];
  f16* dst[4];
  int K[4], N[4];
  int pre[5];
};

__global__ __launch_bounds__(256) void rms_trans_kernel(
    const float* __restrict__ x, const float* __restrict__ w,
    f16* __restrict__ out, TJobs4 a) {
  __shared__ float tile[64][65];
  __shared__ float sred[4];
  int tid = threadIdx.x;
  int bid = blockIdx.x;
  if (bid >= 2048) {
    int t = bid - 2048;
    int job = 0;
    while (job < 3 && t >= a.pre[job + 1]) job++;
    t -= a.pre[job];
    const float* src = a.src[job];
    f16* dst = a.dst[job];
    int K = a.K[job], N = a.N[job];
    int ntn = N >> 6;
    int n0 = (t % ntn) * 64;
    int k0 = (t / ntn) * 64;
#pragma unroll
    for (int i = 0; i < 4; i++) {
      int c = i * 256 + tid;
      int kr = c >> 4, cc = c & 15;
      float4 v = *(const float4*)(src + (long)(k0 + kr) * N + n0 + cc * 4);
      tile[kr][cc * 4 + 0] = v.x;
      tile[kr][cc * 4 + 1] = v.y;
      tile[kr][cc * 4 + 2] = v.z;
      tile[kr][cc * 4 + 3] = v.w;
    }
    __syncthreads();
#pragma unroll
    for (int i = 0; i < 2; i++) {
      int c = i * 256 + tid;
      int nr = c >> 3, kc = (c & 7) * 8;
      union { f16 h[8]; uint4 u; } cv;
#pragma unroll
      for (int jj = 0; jj < 8; jj++) cv.h[jj] = (f16)tile[kc + jj][nr];
      *(uint4*)(dst + (long)(n0 + nr) * K + k0 + kc) = cv.u;
    }
    return;
  }
  long t = bid;
  float4 v = ((const float4*)(x + t * 1024))[tid];
  float ss = v.x * v.x + v.y * v.y + v.z * v.z + v.w * v.w;
  ss = wave_sum64(ss);
  if ((tid & 63) == 0) sred[tid >> 6] = ss;
  __syncthreads();
  float tot = sred[0] + sred[1] + sred[2] + sred[3];
  float sc = rsqrtf(tot * (1.0f / 1024.0f) + 1e-6f);
  float4 wv = ((const float4*)w)[tid];
  union { f16 h[4]; uint2 u; } cv;
  cv.h[0] = (f16)(v.x * wv.x * sc);
  cv.h[1] = (f16)(v.y * wv.y * sc);
  cv.h[2] = (f16)(v.z * wv.z * sc);
  cv.h[3] = (f16)(v.w * wv.w * sc);
  *(uint2*)(out + t * 1024 + tid * 4) = cv.u;
}

// ---------------------------------------------------------------------------
// fused: resid = hidden + P1 + P2 -> OUT(f32); x2 = rms(resid)*w (f16);
// ALSO router: logits = xn . rw -> softmax -> top2/probs; sgate -> pw_shared.
// ---------------------------------------------------------------------------
__global__ __launch_bounds__(256) void rms2r_kernel(
    const float* __restrict__ hidden, const float* __restrict__ p1,
    const float* __restrict__ p2, const float* __restrict__ w,
    const float* __restrict__ rw, const float* __restrict__ segw,
    float* __restrict__ out_resid, f16* __restrict__ x2out,
    int* __restrict__ topi, float* __restrict__ topw,
    float* __restrict__ probs, float* __restrict__ pw_shared) {
  long t = blockIdx.x;
  int tid = threadIdx.x;
  float4 h = ((const float4*)(hidden + t * 1024))[tid];
  float4 a = ((const float4*)(p1 + t * 1024))[tid];
  float4 b = ((const float4*)(p2 + t * 1024))[tid];
  float4 v;
  v.x = h.x + a.x + b.x;
  v.y = h.y + a.y + b.y;
  v.z = h.z + a.z + b.z;
  v.w = h.w + a.w + b.w;
  ((float4*)(out_resid + t * 1024))[tid] = v;
  float ss = v.x * v.x + v.y * v.y + v.z * v.z + v.w * v.w;
  ss = wave_sum64(ss);
  __shared__ float sred[4];
  if ((tid & 63) == 0) sred[tid >> 6] = ss;
  __syncthreads();
  float tot = sred[0] + sred[1] + sred[2] + sred[3];
  float sc = rsqrtf(tot * (1.0f / 1024.0f) + 1e-6f);
  float4 wv = ((const float4*)w)[tid];
  float xa[4];
  xa[0] = v.x * wv.x * sc;
  xa[1] = v.y * wv.y * sc;
  xa[2] = v.z * wv.z * sc;
  xa[3] = v.w * wv.w * sc;
  union { f16 h[4]; uint2 u; } cv;
#pragma unroll
  for (int k = 0; k < 4; k++) cv.h[k] = (f16)xa[k];
  *(uint2*)(x2out + t * 1024 + tid * 4) = cv.u;

  // router logits
  float lacc[8] = {0.f, 0.f, 0.f, 0.f, 0.f, 0.f, 0.f, 0.f};
#pragma unroll
  for (int k = 0; k < 4; k++) {
    const float4* r4 = (const float4*)(rw + (tid * 4 + k) * 8);
    float4 ra = r4[0], rb = r4[1];
    float xk = xa[k];
    lacc[0] += xk * ra.x; lacc[1] += xk * ra.y; lacc[2] += xk * ra.z; lacc[3] += xk * ra.w;
    lacc[4] += xk * rb.x; lacc[5] += xk * rb.y; lacc[6] += xk * rb.z; lacc[7] += xk * rb.w;
  }
  float4 sg4 = ((const float4*)segw)[tid];
  float l9 = xa[0] * sg4.x + xa[1] * sg4.y + xa[2] * sg4.z + xa[3] * sg4.w;
#pragma unroll
  for (int m = 1; m < 64; m <<= 1) {
#pragma unroll
    for (int e = 0; e < 8; e++) lacc[e] += __shfl_xor(lacc[e], m);
    l9 += __shfl_xor(l9, m);
  }
  __shared__ float red[4][9];
  if ((tid & 63) == 0) {
#pragma unroll
    for (int e = 0; e < 8; e++) red[tid >> 6][e] = lacc[e];
    red[tid >> 6][8] = l9;
  }
  __syncthreads();
  if (tid == 0) {
    float p[8];
    float mx = -1e30f;
#pragma unroll
    for (int e = 0; e < 8; e++) {
      p[e] = red[0][e] + red[1][e] + red[2][e] + red[3][e];
      mx = fmaxf(mx, p[e]);
    }
    float l9t = red[0][8] + red[1][8] + red[2][8] + red[3][8];
    pw_shared[t] = 1.0f / (1.0f + expf(-l9t));
    float s = 0.f;
#pragma unroll
    for (int e = 0; e < 8; e++) {
      p[e] = expf(p[e] - mx);
      s += p[e];
    }
    float inv = 1.0f / s;
#pragma unroll
    for (int e = 0; e < 8; e++) p[e] *= inv;
    float4 pa = {p[0], p[1], p[2], p[3]};
    float4 pb = {p[4], p[5], p[6], p[7]};
    *(float4*)(probs + t * 8) = pa;
    *(float4*)(probs + t * 8 + 4) = pb;
    int i1 = 0;
    float b1 = p[0];
#pragma unroll
    for (int e = 1; e < 8; e++)
      if (p[e] > b1) { b1 = p[e]; i1 = e; }
    int i2 = -1;
    float b2 = -1.f;
#pragma unroll
    for (int e = 0; e < 8; e++)
      if (e != i1 && p[e] > b2) { b2 = p[e]; i2 = e; }
    topi[2 * t] = i1;
    topi[2 * t + 1] = i2;
    topw[2 * t] = b1;
    topw[2 * t + 1] = b2;
  }
}

// ---------------------------------------------------------------------------
// GEMM: C[M,N] = A[M,K] * BT[N,K]^T  (f16 in, f32 acc, MFMA 16x16x32)
// 256 threads (4 waves, 2x2), tile 128 x (32*TN), BK=64,
// global_load_lds(16B) staging with XOR-swizzled LDS placement.
// Epilogue LDS uses chunk-XOR swizzle (no padding) to stay at 32KB max.
// MODE 0: dense, f16 out; ROPE=1 applies rotary to cols < 1280 during store.
// MODE 2: dense, f32 out, K-split via blockIdx.z (out += z*estride)
// MODE 5: moe segment (z): A via ptok; B = 64 gate + 64 up rows; epilogue
//         act = silu(g)*u, f16 out rows poff+row (TN must be 4)
// MODE 6: moe segment (z): A rows direct; epilogue atomicAdd of acc*pw into
//         out[ptok[poff+row]*N + col] (f32)
// ---------------------------------------------------------------------------
template <int MODE, int TN, int ROPE>
__global__ __launch_bounds__(256) void gemm_kernel(
    const f16* __restrict__ A, const f16* __restrict__ BT, void* __restrict__ outp,
    const int* __restrict__ ptok, const float* __restrict__ pw,
    const int* __restrict__ segc, const int* __restrict__ sego,
    const int* __restrict__ pos_ids, int N, int K, long estride) {
  const int tile_n = 32 * TN;
  int n0 = blockIdx.x * tile_n;
  int a0 = blockIdx.x * 64;  // MODE5 act-col base
  int m0 = blockIdx.y * 128;
  int cnt = 1 << 30, poff = 0;
  int kbeg = 0, klen = K;
  float* po = (float*)outp;
  if (MODE >= 5) {
    int e = blockIdx.z;
    cnt = segc[e];
    poff = sego[e];
    if (cnt == 0 || m0 >= cnt) return;
    BT += (long)e * estride;
  } else if (MODE == 2) {
    klen = K / gridDim.z;
    kbeg = blockIdx.z * klen;
    po += (long)blockIdx.z * estride;
  }
  constexpr int STAGE = 8192 + 2048 * TN;
  constexpr int EPI = (MODE == 0 || MODE == 5) ? 128 * 32 * TN : 0;
  constexpr int SMEMN = STAGE > EPI ? STAGE : EPI;
  __shared__ f16 smem[SMEMN];
  f16* As = smem;
  f16* Bs = smem + 8192;
  int tid = threadIdx.x;
  int w = tid >> 6, lane = tid & 63;
  int quad = lane >> 4, l16 = lane & 15;
  int wm = (w >> 1) * 64, wn = (w & 1) * (TN * 16);

  const f16* agp[4];
  const f16* bgp[TN];
#pragma unroll
  for (int i = 0; i < 4; i++) {
    int c = i * 256 + tid;
    int r = c >> 3;
    int kq = (c & 7) ^ (r & 7);
    int ar = m0 + r;
    if (MODE == 5) {
      int rr = ar < cnt ? ar : cnt - 1;
      agp[i] = A + (long)ptok[poff + rr] * K + kq * 8;
    } else if (MODE == 6) {
      int rr = ar < cnt ? ar : cnt - 1;
      agp[i] = A + (long)(poff + rr) * K + kq * 8;
    } else {
      agp[i] = A + (long)ar * K + kq * 8;
    }
  }
#pragma unroll
  for (int i = 0; i < TN; i++) {
    int c = i * 256 + tid;
    int r = c >> 3;
    int kq = (c & 7) ^ (r & 7);
    long br;
    if (MODE == 5) br = (r < 64) ? (a0 + r) : (1024 + a0 + (r - 64));
    else br = n0 + r;
    bgp[i] = BT + br * K + kq * 8;
  }

  f32x4 acc[4][TN] = {};

  for (int k0 = kbeg; k0 < kbeg + klen; k0 += 64) {
    __syncthreads();
#pragma unroll
    for (int i = 0; i < 4; i++)
      __builtin_amdgcn_global_load_lds(
          (const __attribute__((address_space(1))) void*)(agp[i] + k0),
          (__attribute__((address_space(3))) void*)(As + (i * 256 + w * 64) * 8),
          16, 0, 0);
#pragma unroll
    for (int i = 0; i < TN; i++)
      __builtin_amdgcn_global_load_lds(
          (const __attribute__((address_space(1))) void*)(bgp[i] + k0),
          (__attribute__((address_space(3))) void*)(Bs + (i * 256 + w * 64) * 8),
          16, 0, 0);
    __syncthreads();
#pragma unroll
    for (int kk = 0; kk < 2; kk++) {
      f16x8 af[4], bf[TN];
      int q = kk * 4 + quad;
#pragma unroll
      for (int i = 0; i < 4; i++) {
        int ra = wm + i * 16 + l16;
        af[i] = *(const f16x8*)&As[ra * 64 + (q ^ (ra & 7)) * 8];
      }
#pragma unroll
      for (int j = 0; j < TN; j++) {
        int rb = wn + j * 16 + l16;
        bf[j] = *(const f16x8*)&Bs[rb * 64 + (q ^ (rb & 7)) * 8];
      }
#pragma unroll
      for (int i = 0; i < 4; i++)
#pragma unroll
        for (int j = 0; j < TN; j++)
          acc[i][j] = __builtin_amdgcn_mfma_f32_16x16x32_f16(af[i], bf[j], acc[i][j], 0, 0, 0);
    }
  }

  if (MODE == 2) {
#pragma unroll
    for (int i = 0; i < 4; i++)
#pragma unroll
      for (int j = 0; j < TN; j++) {
        int col = n0 + wn + j * 16 + l16;
#pragma unroll
        for (int r = 0; r < 4; r++) {
          int row = m0 + wm + i * 16 + quad * 4 + r;
          po[(long)row * N + col] = acc[i][j][r];
        }
      }
  } else if (MODE == 6) {
#pragma unroll
    for (int i = 0; i < 4; i++)
#pragma unroll
      for (int j = 0; j < TN; j++) {
        int col = n0 + wn + j * 16 + l16;
#pragma unroll
        for (int r = 0; r < 4; r++) {
          int row = m0 + wm + i * 16 + quad * 4 + r;
          if (row < cnt) {
            int tok = ptok[poff + row];
            float scl = pw[poff + row];
            atomicAdd(&((float*)outp)[(long)tok * N + col], acc[i][j][r] * scl);
          }
        }
      }
  } else {
    // epilogue via LDS with chunk-XOR swizzle (chunk' = chunk ^ (row&7))
    __syncthreads();
#pragma unroll
    for (int i = 0; i < 4; i++)
#pragma unroll
      for (int j = 0; j < TN; j++)
#pragma unroll
        for (int r = 0; r < 4; r++) {
          int lr = wm + i * 16 + quad * 4 + r;
          int lc = wn + j * 16 + l16;
          int sc_ = ((((lc >> 3) ^ (lr & 7)) << 3) | (lc & 7));
          smem[lr * tile_n + sc_] = (f16)acc[i][j][r];
        }
    __syncthreads();
    if (MODE == 5) {
      // act = silu(gate)*up : gate chunks 0..7, up chunks 8..15 per row
#pragma unroll
      for (int ii = 0; ii < 4; ii++) {
        int c = ii * 256 + tid;
        int row = c >> 3, ci = c & 7;
        int grow = m0 + row;
        if (grow < cnt) {
          int gci = ci ^ (row & 7);
          f16x8 gv = *(const f16x8*)&smem[row * 128 + gci * 8];
          f16x8 uv = *(const f16x8*)&smem[row * 128 + (gci + 8) * 8];
          union { uint4 u; f16 h[8]; } ov;
#pragma unroll
          for (int jj = 0; jj < 8; jj++) {
            float g = (float)gv[jj];
            float u = (float)uv[jj];
            ov.h[jj] = (f16)(g / (1.0f + __expf(-g)) * u);
          }
          *(uint4*)&((f16*)outp)[(long)(poff + grow) * N + a0 + ci * 8] = ov.u;
        }
      }
    } else {
      const int cpr = tile_n / 8;
#pragma unroll
      for (int ii = 0; ii < 2 * TN; ii++) {
        int c = ii * 256 + tid;
        int row = c / cpr, ci = c % cpr;
        int off = ci * 8;
        int grow = m0 + row;
        union { uint4 u; f16 h[8]; } sv;
        sv.u = *(const uint4*)&smem[row * tile_n + (ci ^ (row & 7)) * 8];
        if (ROPE && n0 < 1280) {
          union { uint4 u; f16 h[8]; } pv;
          pv.u = *(const uint4*)&smem[row * tile_n + ((ci ^ 4) ^ (row & 7)) * 8];
          int pos = pos_ids[grow];
          bool low = off < 32;
#pragma unroll
          for (int jj = 0; jj < 8; jj++) {
            int fi = (off & 31) + jj;
            float fr = (float)pos * __expf((float)fi * (-13.815510557964274f / 32.0f));
            float sn, cs;
            sincosf(fr, &sn, &cs);
            float x = (float)sv.h[jj], y = (float)pv.h[jj];
            sv.h[jj] = (f16)(low ? (x * cs - y * sn) : (x * cs + y * sn));
          }
        }
        *(uint4*)&((f16*)outp)[(long)grow * N + n0 + off] = sv.u;
      }
    }
  }
}

// ---------------------------------------------------------------------------
// V transpose: qkv v-section -> vT [B*NKV][64 d][1024 seq]
// ---------------------------------------------------------------------------
__global__ __launch_bounds__(256) void vtrans_kernel(const f16* __restrict__ qkv,
                                                     f16* __restrict__ vT) {
  int bk = blockIdx.x;
  int st = blockIdx.y;
  int b = bk >> 2, kvh = bk & 3;
  int s0 = st * 64;
  int tid = threadIdx.x;
#pragma unroll
  for (int i = 0; i < 2; i++) {
    int c = i * 256 + tid;
    int d = c & 63, sc = c >> 6;
    union { uint4 u; f16 h[8]; } v;
#pragma unroll
    for (int j = 0; j < 8; j++)
      v.h[j] = qkv[(long)(b * SEQ + s0 + sc * 8 + j) * 1536 + 1280 + kvh * 64 + d];
    *(uint4*)&vT[((long)bk * 64 + d) * 1024 + s0 + sc * 8] = v.u;
  }
}

// ---------------------------------------------------------------------------
// MFMA flash attention (blocks 0..511) FUSED with expert/shared weight
// transpose (blocks 512+). Transpose: f32 [1024,1024] -> f16 [1024,1024]^T,
// 128k x 64n region per block (8 in-flight float4 loads, 256B dst segments),
// LDS tile [128][65] f32 aliased onto attn's smem (33.3KB <= 49.2KB).
// Attn blocks dispatched first; the BW-bound transpose streams under the
// MFMA-bound attention on shared CUs.
// ---------------------------------------------------------------------------
struct TJobs27 {
  const float* src[27];
  f16* dst[27];
};

__global__ __launch_bounds__(256) void attn_trans_kernel(
    const f16* __restrict__ qkv, const f16* __restrict__ vT,
    f16* __restrict__ aout, TJobs27 tj) {
  __shared__ f16 smem[24576];  // Qs[64][64] | Ks[128][64] | Vs[64][128] | Ps 4x1024
  int tid = threadIdx.x;
  int bid = blockIdx.x;

  if (bid >= 512) {
    // ---- transpose path ----
    int t = bid - 512;
    int job = t >> 7;          // 128 blocks per 1024x1024 job
    int tt = t & 127;
    int n0 = (tt & 15) << 6;   // 16 n-tiles of 64
    int k0 = (tt >> 4) << 7;   // 8 k-tiles of 128
    const float* src = tj.src[job];
    f16* dst = tj.dst[job];
    float* tile = (float*)smem;  // [128][65] = 33280B
#pragma unroll
    for (int i = 0; i < 8; i++) {
      int c = i * 256 + tid;
      int kr = c >> 4, cc = c & 15;
      float4 v = *(const float4*)(src + (long)(k0 + kr) * 1024 + n0 + cc * 4);
      tile[kr * 65 + cc * 4 + 0] = v.x;
      tile[kr * 65 + cc * 4 + 1] = v.y;
      tile[kr * 65 + cc * 4 + 2] = v.z;
      tile[kr * 65 + cc * 4 + 3] = v.w;
    }
    __syncthreads();
#pragma unroll
    for (int i = 0; i < 4; i++) {
      int c = i * 256 + tid;
      int nr = c >> 4, kc = c & 15;
      union { f16 h[8]; uint4 u; } cv;
#pragma unroll
      for (int jj = 0; jj < 8; jj++) cv.h[jj] = (f16)tile[(kc * 8 + jj) * 65 + nr];
      *(uint4*)(dst + (long)(n0 + nr) * 1024 + k0 + kc * 8) = cv.u;
    }
    return;
  }

  // ---- attention path ----
  int bh = bid & 31;
  int b = bh >> 4, h = bh & 15;
  int kvh = h >> 2;
  int qt = bid >> 5;
  int q0 = qt * 64;
  int w = tid >> 6, lane = tid & 63;
  int quad = lane >> 4, l16 = lane & 15;

  f16* Qs = smem;
  f16* Ks = smem + 4096;
  f16* Vs = smem + 12288;
  f16* Psw = smem + 20480 + w * 1024;

#pragma unroll
  for (int i = 0; i < 2; i++) {
    int c = i * 256 + tid;
    int r = c >> 3;
    int kq = (c & 7) ^ (r & 7);
    __builtin_amdgcn_global_load_lds(
        (const __attribute__((address_space(1))) void*)(qkv + (long)(b * SEQ + q0 + r) * 1536 + h * 64 + kq * 8),
        (__attribute__((address_space(3))) void*)(Qs + c * 8), 16, 0, 0);
  }

  float mr[4], lsum[4];
  f32x4 oacc[4] = {};
#pragma unroll
  for (int r = 0; r < 4; r++) { mr[r] = -1e30f; lsum[r] = 0.f; }

  int nch = (qt + 2) >> 1;
  for (int ch = 0; ch < nch; ch++) {
    __syncthreads();
#pragma unroll
    for (int i = 0; i < 4; i++) {
      int c = i * 256 + tid;
      int r = c >> 3;
      int kq = (c & 7) ^ (r & 7);
      __builtin_amdgcn_global_load_lds(
          (const __attribute__((address_space(1))) void*)(qkv + (long)(b * SEQ + ch * 128 + r) * 1536 + 1024 + kvh * 64 + kq * 8),
          (__attribute__((address_space(3))) void*)(Ks + c * 8), 16, 0, 0);
    }
#pragma unroll
    for (int i = 0; i < 4; i++) {
      int c = i * 256 + tid;
      int d = c >> 4;
      int kq = (c & 15) ^ (d & 15);
      __builtin_amdgcn_global_load_lds(
          (const __attribute__((address_space(1))) void*)(vT + ((long)(b * 4 + kvh) * 64 + d) * 1024 + ch * 128 + kq * 8),
          (__attribute__((address_space(3))) void*)(Vs + c * 8), 16, 0, 0);
    }
    __syncthreads();

    for (int half = 0; half < 2; half++) {
      int kt = ch * 2 + half;
      if (kt > qt) break;

      int m = w * 16 + l16;
      f16x8 aq0 = *(const f16x8*)&Qs[m * 64 + ((quad) ^ (m & 7)) * 8];
      f16x8 aq1 = *(const f16x8*)&Qs[m * 64 + ((4 + quad) ^ (m & 7)) * 8];
      f32x4 sacc[4];
#pragma unroll
      for (int j = 0; j < 4; j++) {
        int n = half * 64 + j * 16 + l16;
        f16x8 bk0 = *(const f16x8*)&Ks[n * 64 + ((quad) ^ (n & 7)) * 8];
        f16x8 bk1 = *(const f16x8*)&Ks[n * 64 + ((4 + quad) ^ (n & 7)) * 8];
        f32x4 z = {};
        z = __builtin_amdgcn_mfma_f32_16x16x32_f16(aq0, bk0, z, 0, 0, 0);
        z = __builtin_amdgcn_mfma_f32_16x16x32_f16(aq1, bk1, z, 0, 0, 0);
        sacc[j] = z;
      }

      bool diag = (kt == qt);
      float sv[4][4];
      float rowmax[4];
#pragma unroll
      for (int r = 0; r < 4; r++) rowmax[r] = -1e30f;
#pragma unroll
      for (int j = 0; j < 4; j++)
#pragma unroll
        for (int r = 0; r < 4; r++) {
          float s = sacc[j][r] * 0.125f;
          if (diag && (j * 16 + l16 > w * 16 + quad * 4 + r)) s = -1e30f;
          sv[j][r] = s;
          rowmax[r] = fmaxf(rowmax[r], s);
        }
#pragma unroll
      for (int r = 0; r < 4; r++) {
        rowmax[r] = fmaxf(rowmax[r], __shfl_xor(rowmax[r], 1));
        rowmax[r] = fmaxf(rowmax[r], __shfl_xor(rowmax[r], 2));
        rowmax[r] = fmaxf(rowmax[r], __shfl_xor(rowmax[r], 4));
        rowmax[r] = fmaxf(rowmax[r], __shfl_xor(rowmax[r], 8));
      }
#pragma unroll
      for (int r = 0; r < 4; r++) {
        float mn = fmaxf(mr[r], rowmax[r]);
        float al = __expf(mr[r] - mn);
        mr[r] = mn;
        float rs = 0.f;
#pragma unroll
        for (int j = 0; j < 4; j++) {
          float pv = __expf(sv[j][r] - mn);
          sv[j][r] = pv;
          rs += pv;
        }
        rs += __shfl_xor(rs, 1);
        rs += __shfl_xor(rs, 2);
        rs += __shfl_xor(rs, 4);
        rs += __shfl_xor(rs, 8);
        lsum[r] = lsum[r] * al + rs;
#pragma unroll
        for (int j = 0; j < 4; j++) oacc[j][r] *= al;
      }

#pragma unroll
      for (int j = 0; j < 4; j++)
#pragma unroll
        for (int r = 0; r < 4; r++) {
          int row = quad * 4 + r;
          int chunk = j * 2 + (l16 >> 3);
          Psw[row * 64 + (chunk ^ (row & 7)) * 8 + (l16 & 7)] = (f16)sv[j][r];
        }

      f16x8 pf0 = *(const f16x8*)&Psw[l16 * 64 + ((quad) ^ (l16 & 7)) * 8];
      f16x8 pf1 = *(const f16x8*)&Psw[l16 * 64 + ((4 + quad) ^ (l16 & 7)) * 8];
#pragma unroll
      for (int j = 0; j < 4; j++) {
        int d = j * 16 + l16;
        f16x8 v0 = *(const f16x8*)&Vs[d * 128 + (((half * 8 + quad) ^ (d & 15))) * 8];
        f16x8 v1 = *(const f16x8*)&Vs[d * 128 + (((half * 8 + 4 + quad) ^ (d & 15))) * 8];
        oacc[j] = __builtin_amdgcn_mfma_f32_16x16x32_f16(pf0, v0, oacc[j], 0, 0, 0);
        oacc[j] = __builtin_amdgcn_mfma_f32_16x16x32_f16(pf1, v1, oacc[j], 0, 0, 0);
      }
    }
  }

  __syncthreads();
  f16* Os = smem;
  float iv[4];
#pragma unroll
  for (int r = 0; r < 4; r++) iv[r] = 1.0f / lsum[r];
#pragma unroll
  for (int j = 0; j < 4; j++)
#pragma unroll
    for (int r = 0; r < 4; r++)
      Os[(w * 16 + quad * 4 + r) * 72 + j * 16 + l16] = (f16)(oacc[j][r] * iv[r]);
  __syncthreads();
#pragma unroll
  for (int i = 0; i < 2; i++) {
    int c = i * 256 + tid;
    int row = c >> 3, off = (c & 7) * 8;
    uint4 v = *(const uint4*)&Os[row * 72 + off];
    *(uint4*)&aout[(long)(b * SEQ + q0 + row) * 1024 + h * 64 + off] = v;
  }
}

// ---------------------------------------------------------------------------
// compact pairs by expert (single block) + psum reduction + aux output.
// Fills segment 8 (shared expert): identity ptok rows 4096..6143.
// ---------------------------------------------------------------------------
__global__ __launch_bounds__(256) void compact_kernel(
    const int* __restrict__ topi, const float* __restrict__ topw, int* __restrict__ segc,
    int* __restrict__ sego, int* __restrict__ ptok, float* __restrict__ pw,
    const float* __restrict__ probs, float* __restrict__ aux_out) {
  __shared__ int c[8];
  __shared__ int off[9];
  __shared__ int cur[8];
  __shared__ float ps[4][8];
  int tid = threadIdx.x;
  if (tid < 8) { c[tid] = 0; cur[tid] = 0; }
  __syncthreads();
  for (int i = tid; i < 4096; i += 256) atomicAdd(&c[topi[i]], 1);
  for (int i = tid; i < 2048; i += 256) ptok[4096 + i] = i;

  float s8[8] = {0.f, 0.f, 0.f, 0.f, 0.f, 0.f, 0.f, 0.f};
  for (int i = tid; i < 2048; i += 256) {
    float4 a = *(const float4*)(probs + i * 8);
    float4 b = *(const float4*)(probs + i * 8 + 4);
    s8[0] += a.x; s8[1] += a.y; s8[2] += a.z; s8[3] += a.w;
    s8[4] += b.x; s8[5] += b.y; s8[6] += b.z; s8[7] += b.w;
  }
#pragma unroll
  for (int e = 0; e < 8; e++) s8[e] = wave_sum64(s8[e]);
  if ((tid & 63) == 0)
#pragma unroll
    for (int e = 0; e < 8; e++) ps[tid >> 6][e] = s8[e];
  __syncthreads();
  if (tid == 0) {
    off[0] = 0;
    for (int e = 0; e < 8; e++) off[e + 1] = off[e] + c[e];
    float a = 0.f;
    for (int e = 0; e < 8; e++) {
      float tot = ps[0][e] + ps[1][e] + ps[2][e] + ps[3][e];
      float d = tot * (1.0f / 2048.0f) - 0.125f;
      a += d * d;
    }
    aux_out[0] = a * (1.0f / 8.0f);
  }
  __syncthreads();
  for (int i = tid; i < 4096; i += 256) {
    int e = topi[i];
    int pidx = atomicAdd(&cur[e], 1);
    int slot = off[e] + pidx;
    ptok[slot] = i >> 1;
    pw[slot] = topw[i];
  }
  if (tid < 8) {
    segc[tid] = c[tid];
    sego[tid] = off[tid];
  }
  if (tid == 0) {
    segc[8] = 2048;
    sego[8] = 4096;
  }
}

// ---------------------------------------------------------------------------
extern "C" void kernel_launch(void* const* d_in, const int* in_sizes, int n_in,
                              void* d_out, int out_size, void* d_ws, size_t ws_size,
                              hipStream_t stream) {
  const float* hidden = (const float*)d_in[0];
  const int* pos_ids = (const int*)d_in[2];
  const float* ln1w = (const float*)d_in[3];
  const float* ln2w = (const float*)d_in[4];
  const float* wq = (const float*)d_in[5];
  const float* wk = (const float*)d_in[6];
  const float* wv = (const float*)d_in[7];
  const float* wo = (const float*)d_in[8];
  const float* router_w = (const float*)d_in[9];
  const float* egw = (const float*)d_in[10];
  const float* euw = (const float*)d_in[11];
  const float* edw = (const float*)d_in[12];
  const float* sgw = (const float*)d_in[13];
  const float* suw = (const float*)d_in[14];
  const float* sdw = (const float*)d_in[15];
  const float* segw = (const float*)d_in[16];
  float* out = (float*)d_out;

  char* p = (char*)d_ws;
  auto alloc = [&](size_t bytes) {
    char* r = p;
    p += (bytes + 255) & ~(size_t)255;
    return r;
  };
  f16* wqkvT = (f16*)alloc(1536l * 1024 * 2);
  f16* woT = (f16*)alloc(1024l * 1024 * 2);
  f16* guT = (f16*)alloc(9l * 2048 * 1024 * 2);   // experts 0-7 + shared(8)
  f16* dnT = (f16*)alloc(9l * 1024 * 1024 * 2);
  f16* xln1 = (f16*)alloc(2048l * 1024 * 2);
  f16* qkv = (f16*)alloc(2048l * 1536 * 2);
  f16* vT = (f16*)alloc(8l * 64 * 1024 * 2);
  f16* attnO = (f16*)alloc(2048l * 1024 * 2);
  float* wo_part = (float*)alloc(2l * 2048 * 1024 * 4);
  f16* x2 = (f16*)alloc(2048l * 1024 * 2);
  f16* act_all = (f16*)alloc(6144l * 1024 * 2);
  int* topi = (int*)alloc(4096 * 4);
  float* topw = (float*)alloc(4096 * 4);
  float* probs = (float*)alloc(2048l * 8 * 4);
  int* ptok = (int*)alloc(6144 * 4);
  float* pwts = (float*)alloc(6144 * 4);
  int* segc = (int*)alloc(9 * 4);
  int* sego = (int*)alloc(9 * 4);

  // ---- attention-path weight transposes, fused with RMSNorm launch ----
  TJobs4 tj4;
  int nj = 0, pre = 0;
  auto addjob4 = [&](const float* s, f16* d, int K, int N) {
    tj4.src[nj] = s; tj4.dst[nj] = d; tj4.K[nj] = K; tj4.N[nj] = N;
    tj4.pre[nj] = pre;
    pre += (N >> 6) * (K >> 6);
    nj++;
  };
  addjob4(wq, wqkvT, 1024, 1024);
  addjob4(wk, wqkvT + 1024l * 1024, 1024, 256);
  addjob4(wv, wqkvT + 1280l * 1024, 1024, 256);
  addjob4(wo, woT, 1024, 1024);
  tj4.pre[nj] = pre;  // sentinel (pre == 640)

  // ---- expert + shared weight transposes, fused with attention launch ----
  TJobs27 tj27;
  int j27 = 0;
  for (int e = 0; e < 8; e++) {
    tj27.src[j27] = egw + (long)e * 1024 * 1024; tj27.dst[j27] = guT + (long)e * 2048 * 1024; j27++;
    tj27.src[j27] = euw + (long)e * 1024 * 1024; tj27.dst[j27] = guT + (long)e * 2048 * 1024 + 1024l * 1024; j27++;
    tj27.src[j27] = edw + (long)e * 1024 * 1024; tj27.dst[j27] = dnT + (long)e * 1024 * 1024; j27++;
  }
  tj27.src[j27] = sgw; tj27.dst[j27] = guT + 8l * 2048 * 1024; j27++;
  tj27.src[j27] = suw; tj27.dst[j27] = guT + 8l * 2048 * 1024 + 1024l * 1024; j27++;
  tj27.src[j27] = sdw; tj27.dst[j27] = dnT + 8l * 1024 * 1024; j27++;

  // attention path (rope fused into QKV epilogue)
  rms_trans_kernel<<<2048 + pre, 256, 0, stream>>>(hidden, ln1w, xln1, tj4);
  gemm_kernel<0, 2, 1><<<dim3(24, 16, 1), 256, 0, stream>>>(xln1, wqkvT, qkv, nullptr, nullptr, nullptr, nullptr, pos_ids, 1536, 1024, 0);
  vtrans_kernel<<<dim3(8, 16, 1), 256, 0, stream>>>(qkv, vT);
  attn_trans_kernel<<<512 + 27 * 128, 256, 0, stream>>>(qkv, vT, attnO, tj27);
  // WO: K-split x2 into f32 partials; rms2r combines into OUT(resid) + x2 + router
  gemm_kernel<2, 2, 0><<<dim3(16, 16, 2), 256, 0, stream>>>(attnO, woT, wo_part, nullptr, nullptr, nullptr, nullptr, nullptr, 1024, 1024, 2048l * 1024);
  rms2r_kernel<<<2048, 256, 0, stream>>>(hidden, wo_part, wo_part + 2048l * 1024, ln2w, router_w, segw, out, x2, topi, topw, probs, pwts + 4096);

  // MoE path (shared expert = segment 8; its pw = sgate from router)
  compact_kernel<<<1, 256, 0, stream>>>(topi, topw, segc, sego, ptok, pwts, probs, out + 2097152);

  gemm_kernel<5, 4, 0><<<dim3(16, 16, 9), 256, 0, stream>>>(x2, guT, act_all, ptok, nullptr, segc, sego, nullptr, 1024, 1024, 2048l * 1024);
  gemm_kernel<6, 2, 0><<<dim3(16, 16, 9), 256, 0, stream>>>(act_all, dnT, out, ptok, pwts, segc, sego, nullptr, 1024, 1024, 1024l * 1024);
}

// Round 2
// 345.756 us; speedup vs baseline: 1.0971x; 1.0197x over previous
//
#include <hip/hip_runtime.h>
#include <cstdint>
#include <cstddef>

typedef _Float16 f16;
typedef _Float16 f16x8 __attribute__((ext_vector_type(8)));
typedef float f32x4 __attribute__((ext_vector_type(4)));

#define SEQ 1024

// ---------------------------------------------------------------------------
// helpers
// ---------------------------------------------------------------------------
__device__ __forceinline__ float wave_sum64(float v) {
#pragma unroll
  for (int m = 1; m < 64; m <<= 1) v += __shfl_xor(v, m);
  return v;
}

// ---------------------------------------------------------------------------
// fused: RMSNorm (blocks 0..2047) + attention-weight transpose (blocks 2048+)
// transpose: f32 [K,N] -> f16 [N,K], 64x64 tiles (wq/wk/wv/wo only).
// ---------------------------------------------------------------------------
struct TJobs4 {
  const float* src[4];
  f16* dst[4];
  int K[4], N[4];
  int pre[5];
};

__global__ __launch_bounds__(256) void rms_trans_kernel(
    const float* __restrict__ x, const float* __restrict__ w,
    f16* __restrict__ out, TJobs4 a) {
  __shared__ float tile[64][65];
  __shared__ float sred[4];
  int tid = threadIdx.x;
  int bid = blockIdx.x;
  if (bid >= 2048) {
    int t = bid - 2048;
    int job = 0;
    while (job < 3 && t >= a.pre[job + 1]) job++;
    t -= a.pre[job];
    const float* src = a.src[job];
    f16* dst = a.dst[job];
    int K = a.K[job], N = a.N[job];
    int ntn = N >> 6;
    int n0 = (t % ntn) * 64;
    int k0 = (t / ntn) * 64;
#pragma unroll
    for (int i = 0; i < 4; i++) {
      int c = i * 256 + tid;
      int kr = c >> 4, cc = c & 15;
      float4 v = *(const float4*)(src + (long)(k0 + kr) * N + n0 + cc * 4);
      tile[kr][cc * 4 + 0] = v.x;
      tile[kr][cc * 4 + 1] = v.y;
      tile[kr][cc * 4 + 2] = v.z;
      tile[kr][cc * 4 + 3] = v.w;
    }
    __syncthreads();
#pragma unroll
    for (int i = 0; i < 2; i++) {
      int c = i * 256 + tid;
      int nr = c >> 3, kc = (c & 7) * 8;
      union { f16 h[8]; uint4 u; } cv;
#pragma unroll
      for (int jj = 0; jj < 8; jj++) cv.h[jj] = (f16)tile[kc + jj][nr];
      *(uint4*)(dst + (long)(n0 + nr) * K + k0 + kc) = cv.u;
    }
    return;
  }
  long t = bid;
  float4 v = ((const float4*)(x + t * 1024))[tid];
  float ss = v.x * v.x + v.y * v.y + v.z * v.z + v.w * v.w;
  ss = wave_sum64(ss);
  if ((tid & 63) == 0) sred[tid >> 6] = ss;
  __syncthreads();
  float tot = sred[0] + sred[1] + sred[2] + sred[3];
  float sc = rsqrtf(tot * (1.0f / 1024.0f) + 1e-6f);
  float4 wv = ((const float4*)w)[tid];
  union { f16 h[4]; uint2 u; } cv;
  cv.h[0] = (f16)(v.x * wv.x * sc);
  cv.h[1] = (f16)(v.y * wv.y * sc);
  cv.h[2] = (f16)(v.z * wv.z * sc);
  cv.h[3] = (f16)(v.w * wv.w * sc);
  *(uint2*)(out + t * 1024 + tid * 4) = cv.u;
}

// ---------------------------------------------------------------------------
// fused: resid = hidden + P1 + P2 -> OUT(f32); x2 = rms(resid)*w (f16);
// ALSO router: logits = xn . rw -> softmax -> top2/probs; sgate -> pw_shared.
// ---------------------------------------------------------------------------
__global__ __launch_bounds__(256) void rms2r_kernel(
    const float* __restrict__ hidden, const float* __restrict__ p1,
    const float* __restrict__ p2, const float* __restrict__ w,
    const float* __restrict__ rw, const float* __restrict__ segw,
    float* __restrict__ out_resid, f16* __restrict__ x2out,
    int* __restrict__ topi, float* __restrict__ topw,
    float* __restrict__ probs, float* __restrict__ pw_shared) {
  long t = blockIdx.x;
  int tid = threadIdx.x;
  float4 h = ((const float4*)(hidden + t * 1024))[tid];
  float4 a = ((const float4*)(p1 + t * 1024))[tid];
  float4 b = ((const float4*)(p2 + t * 1024))[tid];
  float4 v;
  v.x = h.x + a.x + b.x;
  v.y = h.y + a.y + b.y;
  v.z = h.z + a.z + b.z;
  v.w = h.w + a.w + b.w;
  ((float4*)(out_resid + t * 1024))[tid] = v;
  float ss = v.x * v.x + v.y * v.y + v.z * v.z + v.w * v.w;
  ss = wave_sum64(ss);
  __shared__ float sred[4];
  if ((tid & 63) == 0) sred[tid >> 6] = ss;
  __syncthreads();
  float tot = sred[0] + sred[1] + sred[2] + sred[3];
  float sc = rsqrtf(tot * (1.0f / 1024.0f) + 1e-6f);
  float4 wv = ((const float4*)w)[tid];
  float xa[4];
  xa[0] = v.x * wv.x * sc;
  xa[1] = v.y * wv.y * sc;
  xa[2] = v.z * wv.z * sc;
  xa[3] = v.w * wv.w * sc;
  union { f16 h[4]; uint2 u; } cv;
#pragma unroll
  for (int k = 0; k < 4; k++) cv.h[k] = (f16)xa[k];
  *(uint2*)(x2out + t * 1024 + tid * 4) = cv.u;

  // router logits
  float lacc[8] = {0.f, 0.f, 0.f, 0.f, 0.f, 0.f, 0.f, 0.f};
#pragma unroll
  for (int k = 0; k < 4; k++) {
    const float4* r4 = (const float4*)(rw + (tid * 4 + k) * 8);
    float4 ra = r4[0], rb = r4[1];
    float xk = xa[k];
    lacc[0] += xk * ra.x; lacc[1] += xk * ra.y; lacc[2] += xk * ra.z; lacc[3] += xk * ra.w;
    lacc[4] += xk * rb.x; lacc[5] += xk * rb.y; lacc[6] += xk * rb.z; lacc[7] += xk * rb.w;
  }
  float4 sg4 = ((const float4*)segw)[tid];
  float l9 = xa[0] * sg4.x + xa[1] * sg4.y + xa[2] * sg4.z + xa[3] * sg4.w;
#pragma unroll
  for (int m = 1; m < 64; m <<= 1) {
#pragma unroll
    for (int e = 0; e < 8; e++) lacc[e] += __shfl_xor(lacc[e], m);
    l9 += __shfl_xor(l9, m);
  }
  __shared__ float red[4][9];
  if ((tid & 63) == 0) {
#pragma unroll
    for (int e = 0; e < 8; e++) red[tid >> 6][e] = lacc[e];
    red[tid >> 6][8] = l9;
  }
  __syncthreads();
  if (tid == 0) {
    float p[8];
    float mx = -1e30f;
#pragma unroll
    for (int e = 0; e < 8; e++) {
      p[e] = red[0][e] + red[1][e] + red[2][e] + red[3][e];
      mx = fmaxf(mx, p[e]);
    }
    float l9t = red[0][8] + red[1][8] + red[2][8] + red[3][8];
    pw_shared[t] = 1.0f / (1.0f + expf(-l9t));
    float s = 0.f;
#pragma unroll
    for (int e = 0; e < 8; e++) {
      p[e] = expf(p[e] - mx);
      s += p[e];
    }
    float inv = 1.0f / s;
#pragma unroll
    for (int e = 0; e < 8; e++) p[e] *= inv;
    float4 pa = {p[0], p[1], p[2], p[3]};
    float4 pb = {p[4], p[5], p[6], p[7]};
    *(float4*)(probs + t * 8) = pa;
    *(float4*)(probs + t * 8 + 4) = pb;
    int i1 = 0;
    float b1 = p[0];
#pragma unroll
    for (int e = 1; e < 8; e++)
      if (p[e] > b1) { b1 = p[e]; i1 = e; }
    int i2 = -1;
    float b2 = -1.f;
#pragma unroll
    for (int e = 0; e < 8; e++)
      if (e != i1 && p[e] > b2) { b2 = p[e]; i2 = e; }
    topi[2 * t] = i1;
    topi[2 * t + 1] = i2;
    topw[2 * t] = b1;
    topw[2 * t + 1] = b2;
  }
}

// ---------------------------------------------------------------------------
// GEMM: C[M,N] = A[M,K] * BT[N,K]^T  (f16 in, f32 acc, MFMA 16x16x32)
// 256 threads (4 waves, 2x2), tile 128 x (32*TN), BK=64,
// DOUBLE-BUFFERED global_load_lds(16B) staging with XOR-swizzled placement:
// stage tile k+1 into buf^1 while computing tile k from buf (one barrier/K-step).
// MODE 0: dense, f16 out; ROPE=1 applies rotary to cols < 1280 during store.
// MODE 2: dense, f32 out, K-split via blockIdx.z (out += z*estride)
// MODE 5: moe, flattened worklist over blockIdx.y (shared expert first);
//         B = 64 gate + 64 up rows; epilogue act = silu(g)*u (TN must be 4)
// MODE 6: moe, flattened worklist; epilogue atomicAdd of acc*pw into
//         out[ptok[poff+row]*N + col] (f32)
// ---------------------------------------------------------------------------
template <int MODE, int TN, int ROPE>
__global__ __launch_bounds__(256) void gemm_kernel(
    const f16* __restrict__ A, const f16* __restrict__ BT, void* __restrict__ outp,
    const int* __restrict__ ptok, const float* __restrict__ pw,
    const int* __restrict__ segc, const int* __restrict__ sego,
    const int* __restrict__ pos_ids, int N, int K, long estride) {
  const int tile_n = 32 * TN;
  int n0 = blockIdx.x * tile_n;
  int a0 = blockIdx.x * 64;  // MODE5 act-col base
  int m0 = blockIdx.y * 128;
  int cnt = 1 << 30, poff = 0;
  int kbeg = 0, klen = K;
  float* po = (float*)outp;
  if (MODE >= 5) {
    // flattened worklist: mt 0..15 -> shared expert (seg 8), dispatched first;
    // mt 16+ -> routed expert m-tiles packed in expert order.
    int mt = blockIdx.y;
    int e, lm;
    if (mt < 16) {
      e = 8; lm = mt;
    } else {
      int r = mt - 16;
      e = 0;
      while (e < 8) {
        int nt = (segc[e] + 127) >> 7;
        if (r < nt) break;
        r -= nt;
        e++;
      }
      if (e == 8) return;
      lm = r;
    }
    cnt = segc[e];
    poff = sego[e];
    m0 = lm * 128;
    if (cnt == 0 || m0 >= cnt) return;
    BT += (long)e * estride;
  } else if (MODE == 2) {
    klen = K / gridDim.z;
    kbeg = blockIdx.z * klen;
    po += (long)blockIdx.z * estride;
  }
  constexpr int STAGE = 8192 + 2048 * TN;  // f16 elems per buffer
  constexpr int EPI = (MODE == 0 || MODE == 5) ? 128 * 32 * TN : 0;
  constexpr int DBUF = 2 * STAGE;
  constexpr int SMEMN = DBUF > EPI ? DBUF : EPI;
  __shared__ f16 smem[SMEMN];
  int tid = threadIdx.x;
  int w = tid >> 6, lane = tid & 63;
  int quad = lane >> 4, l16 = lane & 15;
  int wm = (w >> 1) * 64, wn = (w & 1) * (TN * 16);

  const f16* agp[4];
  const f16* bgp[TN];
#pragma unroll
  for (int i = 0; i < 4; i++) {
    int c = i * 256 + tid;
    int r = c >> 3;
    int kq = (c & 7) ^ (r & 7);
    int ar = m0 + r;
    if (MODE == 5) {
      int rr = ar < cnt ? ar : cnt - 1;
      agp[i] = A + (long)ptok[poff + rr] * K + kq * 8;
    } else if (MODE == 6) {
      int rr = ar < cnt ? ar : cnt - 1;
      agp[i] = A + (long)(poff + rr) * K + kq * 8;
    } else {
      agp[i] = A + (long)ar * K + kq * 8;
    }
  }
#pragma unroll
  for (int i = 0; i < TN; i++) {
    int c = i * 256 + tid;
    int r = c >> 3;
    int kq = (c & 7) ^ (r & 7);
    long br;
    if (MODE == 5) br = (r < 64) ? (a0 + r) : (1024 + a0 + (r - 64));
    else br = n0 + r;
    bgp[i] = BT + br * K + kq * 8;
  }

  auto stage = [&](int kk0, int buf) {
    f16* dstA = smem + buf * STAGE;
    f16* dstB = dstA + 8192;
#pragma unroll
    for (int i = 0; i < 4; i++)
      __builtin_amdgcn_global_load_lds(
          (const __attribute__((address_space(1))) void*)(agp[i] + kk0),
          (__attribute__((address_space(3))) void*)(dstA + (i * 256 + w * 64) * 8),
          16, 0, 0);
#pragma unroll
    for (int i = 0; i < TN; i++)
      __builtin_amdgcn_global_load_lds(
          (const __attribute__((address_space(1))) void*)(bgp[i] + kk0),
          (__attribute__((address_space(3))) void*)(dstB + (i * 256 + w * 64) * 8),
          16, 0, 0);
  };

  f32x4 acc[4][TN] = {};

  stage(kbeg, 0);
  __syncthreads();  // drains vmcnt(0): buf0 ready
  int cur = 0;
  for (int k0 = kbeg; k0 < kbeg + klen; k0 += 64) {
    if (k0 + 64 < kbeg + klen) stage(k0 + 64, cur ^ 1);  // prefetch next tile
    const f16* As = smem + cur * STAGE;
    const f16* Bs = As + 8192;
#pragma unroll
    for (int kk = 0; kk < 2; kk++) {
      f16x8 af[4], bf[TN];
      int q = kk * 4 + quad;
#pragma unroll
      for (int i = 0; i < 4; i++) {
        int ra = wm + i * 16 + l16;
        af[i] = *(const f16x8*)&As[ra * 64 + (q ^ (ra & 7)) * 8];
      }
#pragma unroll
      for (int j = 0; j < TN; j++) {
        int rb = wn + j * 16 + l16;
        bf[j] = *(const f16x8*)&Bs[rb * 64 + (q ^ (rb & 7)) * 8];
      }
#pragma unroll
      for (int i = 0; i < 4; i++)
#pragma unroll
        for (int j = 0; j < TN; j++)
          acc[i][j] = __builtin_amdgcn_mfma_f32_16x16x32_f16(af[i], bf[j], acc[i][j], 0, 0, 0);
    }
    __syncthreads();  // drains vmcnt(0): next buf ready, this buf free
    cur ^= 1;
  }

  if (MODE == 2) {
#pragma unroll
    for (int i = 0; i < 4; i++)
#pragma unroll
      for (int j = 0; j < TN; j++) {
        int col = n0 + wn + j * 16 + l16;
#pragma unroll
        for (int r = 0; r < 4; r++) {
          int row = m0 + wm + i * 16 + quad * 4 + r;
          po[(long)row * N + col] = acc[i][j][r];
        }
      }
  } else if (MODE == 6) {
#pragma unroll
    for (int i = 0; i < 4; i++)
#pragma unroll
      for (int j = 0; j < TN; j++) {
        int col = n0 + wn + j * 16 + l16;
#pragma unroll
        for (int r = 0; r < 4; r++) {
          int row = m0 + wm + i * 16 + quad * 4 + r;
          if (row < cnt) {
            int tok = ptok[poff + row];
            float scl = pw[poff + row];
            atomicAdd(&((float*)outp)[(long)tok * N + col], acc[i][j][r] * scl);
          }
        }
      }
  } else {
    // epilogue via LDS with chunk-XOR swizzle (chunk' = chunk ^ (row&7))
    __syncthreads();
#pragma unroll
    for (int i = 0; i < 4; i++)
#pragma unroll
      for (int j = 0; j < TN; j++)
#pragma unroll
        for (int r = 0; r < 4; r++) {
          int lr = wm + i * 16 + quad * 4 + r;
          int lc = wn + j * 16 + l16;
          int sc_ = ((((lc >> 3) ^ (lr & 7)) << 3) | (lc & 7));
          smem[lr * tile_n + sc_] = (f16)acc[i][j][r];
        }
    __syncthreads();
    if (MODE == 5) {
      // act = silu(gate)*up : gate chunks 0..7, up chunks 8..15 per row
#pragma unroll
      for (int ii = 0; ii < 4; ii++) {
        int c = ii * 256 + tid;
        int row = c >> 3, ci = c & 7;
        int grow = m0 + row;
        if (grow < cnt) {
          int gci = ci ^ (row & 7);
          f16x8 gv = *(const f16x8*)&smem[row * 128 + gci * 8];
          f16x8 uv = *(const f16x8*)&smem[row * 128 + (gci + 8) * 8];
          union { uint4 u; f16 h[8]; } ov;
#pragma unroll
          for (int jj = 0; jj < 8; jj++) {
            float g = (float)gv[jj];
            float u = (float)uv[jj];
            ov.h[jj] = (f16)(g / (1.0f + __expf(-g)) * u);
          }
          *(uint4*)&((f16*)outp)[(long)(poff + grow) * N + a0 + ci * 8] = ov.u;
        }
      }
    } else {
      const int cpr = tile_n / 8;
#pragma unroll
      for (int ii = 0; ii < 2 * TN; ii++) {
        int c = ii * 256 + tid;
        int row = c / cpr, ci = c % cpr;
        int off = ci * 8;
        int grow = m0 + row;
        union { uint4 u; f16 h[8]; } sv;
        sv.u = *(const uint4*)&smem[row * tile_n + (ci ^ (row & 7)) * 8];
        if (ROPE && n0 < 1280) {
          union { uint4 u; f16 h[8]; } pv;
          pv.u = *(const uint4*)&smem[row * tile_n + ((ci ^ 4) ^ (row & 7)) * 8];
          int pos = pos_ids[grow];
          bool low = off < 32;
#pragma unroll
          for (int jj = 0; jj < 8; jj++) {
            int fi = (off & 31) + jj;
            float fr = (float)pos * __expf((float)fi * (-13.815510557964274f / 32.0f));
            float sn, cs;
            sincosf(fr, &sn, &cs);
            float x = (float)sv.h[jj], y = (float)pv.h[jj];
            sv.h[jj] = (f16)(low ? (x * cs - y * sn) : (x * cs + y * sn));
          }
        }
        *(uint4*)&((f16*)outp)[(long)grow * N + n0 + off] = sv.u;
      }
    }
  }
}

// ---------------------------------------------------------------------------
// V transpose: qkv v-section -> vT [B*NKV][64 d][1024 seq]
// ---------------------------------------------------------------------------
__global__ __launch_bounds__(256) void vtrans_kernel(const f16* __restrict__ qkv,
                                                     f16* __restrict__ vT) {
  int bk = blockIdx.x;
  int st = blockIdx.y;
  int b = bk >> 2, kvh = bk & 3;
  int s0 = st * 64;
  int tid = threadIdx.x;
#pragma unroll
  for (int i = 0; i < 2; i++) {
    int c = i * 256 + tid;
    int d = c & 63, sc = c >> 6;
    union { uint4 u; f16 h[8]; } v;
#pragma unroll
    for (int j = 0; j < 8; j++)
      v.h[j] = qkv[(long)(b * SEQ + s0 + sc * 8 + j) * 1536 + 1280 + kvh * 64 + d];
    *(uint4*)&vT[((long)bk * 64 + d) * 1024 + s0 + sc * 8] = v.u;
  }
}

// ---------------------------------------------------------------------------
// MFMA flash attention (blocks 0..511) FUSED with expert/shared weight
// transpose (blocks 512+). Transpose: f32 [1024,1024] -> f16 [1024,1024]^T,
// 128k x 64n region per block, LDS tile [128][65] f32 aliased onto attn smem.
// ---------------------------------------------------------------------------
struct TJobs27 {
  const float* src[27];
  f16* dst[27];
};

__global__ __launch_bounds__(256) void attn_trans_kernel(
    const f16* __restrict__ qkv, const f16* __restrict__ vT,
    f16* __restrict__ aout, TJobs27 tj) {
  __shared__ f16 smem[24576];  // Qs[64][64] | Ks[128][64] | Vs[64][128] | Ps 4x1024
  int tid = threadIdx.x;
  int bid = blockIdx.x;

  if (bid >= 512) {
    // ---- transpose path ----
    int t = bid - 512;
    int job = t >> 7;          // 128 blocks per 1024x1024 job
    int tt = t & 127;
    int n0 = (tt & 15) << 6;   // 16 n-tiles of 64
    int k0 = (tt >> 4) << 7;   // 8 k-tiles of 128
    const float* src = tj.src[job];
    f16* dst = tj.dst[job];
    float* tile = (float*)smem;  // [128][65] = 33280B
#pragma unroll
    for (int i = 0; i < 8; i++) {
      int c = i * 256 + tid;
      int kr = c >> 4, cc = c & 15;
      float4 v = *(const float4*)(src + (long)(k0 + kr) * 1024 + n0 + cc * 4);
      tile[kr * 65 + cc * 4 + 0] = v.x;
      tile[kr * 65 + cc * 4 + 1] = v.y;
      tile[kr * 65 + cc * 4 + 2] = v.z;
      tile[kr * 65 + cc * 4 + 3] = v.w;
    }
    __syncthreads();
#pragma unroll
    for (int i = 0; i < 4; i++) {
      int c = i * 256 + tid;
      int nr = c >> 4, kc = c & 15;
      union { f16 h[8]; uint4 u; } cv;
#pragma unroll
      for (int jj = 0; jj < 8; jj++) cv.h[jj] = (f16)tile[(kc * 8 + jj) * 65 + nr];
      *(uint4*)(dst + (long)(n0 + nr) * 1024 + k0 + kc * 8) = cv.u;
    }
    return;
  }

  // ---- attention path ----
  int bh = bid & 31;
  int b = bh >> 4, h = bh & 15;
  int kvh = h >> 2;
  int qt = bid >> 5;
  int q0 = qt * 64;
  int w = tid >> 6, lane = tid & 63;
  int quad = lane >> 4, l16 = lane & 15;

  f16* Qs = smem;
  f16* Ks = smem + 4096;
  f16* Vs = smem + 12288;
  f16* Psw = smem + 20480 + w * 1024;

#pragma unroll
  for (int i = 0; i < 2; i++) {
    int c = i * 256 + tid;
    int r = c >> 3;
    int kq = (c & 7) ^ (r & 7);
    __builtin_amdgcn_global_load_lds(
        (const __attribute__((address_space(1))) void*)(qkv + (long)(b * SEQ + q0 + r) * 1536 + h * 64 + kq * 8),
        (__attribute__((address_space(3))) void*)(Qs + c * 8), 16, 0, 0);
  }

  float mr[4], lsum[4];
  f32x4 oacc[4] = {};
#pragma unroll
  for (int r = 0; r < 4; r++) { mr[r] = -1e30f; lsum[r] = 0.f; }

  int nch = (qt + 2) >> 1;
  for (int ch = 0; ch < nch; ch++) {
    __syncthreads();
#pragma unroll
    for (int i = 0; i < 4; i++) {
      int c = i * 256 + tid;
      int r = c >> 3;
      int kq = (c & 7) ^ (r & 7);
      __builtin_amdgcn_global_load_lds(
          (const __attribute__((address_space(1))) void*)(qkv + (long)(b * SEQ + ch * 128 + r) * 1536 + 1024 + kvh * 64 + kq * 8),
          (__attribute__((address_space(3))) void*)(Ks + c * 8), 16, 0, 0);
    }
#pragma unroll
    for (int i = 0; i < 4; i++) {
      int c = i * 256 + tid;
      int d = c >> 4;
      int kq = (c & 15) ^ (d & 15);
      __builtin_amdgcn_global_load_lds(
          (const __attribute__((address_space(1))) void*)(vT + ((long)(b * 4 + kvh) * 64 + d) * 1024 + ch * 128 + kq * 8),
          (__attribute__((address_space(3))) void*)(Vs + c * 8), 16, 0, 0);
    }
    __syncthreads();

    for (int half = 0; half < 2; half++) {
      int kt = ch * 2 + half;
      if (kt > qt) break;

      int m = w * 16 + l16;
      f16x8 aq0 = *(const f16x8*)&Qs[m * 64 + ((quad) ^ (m & 7)) * 8];
      f16x8 aq1 = *(const f16x8*)&Qs[m * 64 + ((4 + quad) ^ (m & 7)) * 8];
      f32x4 sacc[4];
#pragma unroll
      for (int j = 0; j < 4; j++) {
        int n = half * 64 + j * 16 + l16;
        f16x8 bk0 = *(const f16x8*)&Ks[n * 64 + ((quad) ^ (n & 7)) * 8];
        f16x8 bk1 = *(const f16x8*)&Ks[n * 64 + ((4 + quad) ^ (n & 7)) * 8];
        f32x4 z = {};
        z = __builtin_amdgcn_mfma_f32_16x16x32_f16(aq0, bk0, z, 0, 0, 0);
        z = __builtin_amdgcn_mfma_f32_16x16x32_f16(aq1, bk1, z, 0, 0, 0);
        sacc[j] = z;
      }

      bool diag = (kt == qt);
      float sv[4][4];
      float rowmax[4];
#pragma unroll
      for (int r = 0; r < 4; r++) rowmax[r] = -1e30f;
#pragma unroll
      for (int j = 0; j < 4; j++)
#pragma unroll
        for (int r = 0; r < 4; r++) {
          float s = sacc[j][r] * 0.125f;
          if (diag && (j * 16 + l16 > w * 16 + quad * 4 + r)) s = -1e30f;
          sv[j][r] = s;
          rowmax[r] = fmaxf(rowmax[r], s);
        }
#pragma unroll
      for (int r = 0; r < 4; r++) {
        rowmax[r] = fmaxf(rowmax[r], __shfl_xor(rowmax[r], 1));
        rowmax[r] = fmaxf(rowmax[r], __shfl_xor(rowmax[r], 2));
        rowmax[r] = fmaxf(rowmax[r], __shfl_xor(rowmax[r], 4));
        rowmax[r] = fmaxf(rowmax[r], __shfl_xor(rowmax[r], 8));
      }
#pragma unroll
      for (int r = 0; r < 4; r++) {
        float mn = fmaxf(mr[r], rowmax[r]);
        float al = __expf(mr[r] - mn);
        mr[r] = mn;
        float rs = 0.f;
#pragma unroll
        for (int j = 0; j < 4; j++) {
          float pv = __expf(sv[j][r] - mn);
          sv[j][r] = pv;
          rs += pv;
        }
        rs += __shfl_xor(rs, 1);
        rs += __shfl_xor(rs, 2);
        rs += __shfl_xor(rs, 4);
        rs += __shfl_xor(rs, 8);
        lsum[r] = lsum[r] * al + rs;
#pragma unroll
        for (int j = 0; j < 4; j++) oacc[j][r] *= al;
      }

#pragma unroll
      for (int j = 0; j < 4; j++)
#pragma unroll
        for (int r = 0; r < 4; r++) {
          int row = quad * 4 + r;
          int chunk = j * 2 + (l16 >> 3);
          Psw[row * 64 + (chunk ^ (row & 7)) * 8 + (l16 & 7)] = (f16)sv[j][r];
        }

      f16x8 pf0 = *(const f16x8*)&Psw[l16 * 64 + ((quad) ^ (l16 & 7)) * 8];
      f16x8 pf1 = *(const f16x8*)&Psw[l16 * 64 + ((4 + quad) ^ (l16 & 7)) * 8];
#pragma unroll
      for (int j = 0; j < 4; j++) {
        int d = j * 16 + l16;
        f16x8 v0 = *(const f16x8*)&Vs[d * 128 + (((half * 8 + quad) ^ (d & 15))) * 8];
        f16x8 v1 = *(const f16x8*)&Vs[d * 128 + (((half * 8 + 4 + quad) ^ (d & 15))) * 8];
        oacc[j] = __builtin_amdgcn_mfma_f32_16x16x32_f16(pf0, v0, oacc[j], 0, 0, 0);
        oacc[j] = __builtin_amdgcn_mfma_f32_16x16x32_f16(pf1, v1, oacc[j], 0, 0, 0);
      }
    }
  }

  __syncthreads();
  f16* Os = smem;
  float iv[4];
#pragma unroll
  for (int r = 0; r < 4; r++) iv[r] = 1.0f / lsum[r];
#pragma unroll
  for (int j = 0; j < 4; j++)
#pragma unroll
    for (int r = 0; r < 4; r++)
      Os[(w * 16 + quad * 4 + r) * 72 + j * 16 + l16] = (f16)(oacc[j][r] * iv[r]);
  __syncthreads();
#pragma unroll
  for (int i = 0; i < 2; i++) {
    int c = i * 256 + tid;
    int row = c >> 3, off = (c & 7) * 8;
    uint4 v = *(const uint4*)&Os[row * 72 + off];
    *(uint4*)&aout[(long)(b * SEQ + q0 + row) * 1024 + h * 64 + off] = v;
  }
}

// ---------------------------------------------------------------------------
// compact pairs by expert (single block) + psum reduction + aux output.
// Fills segment 8 (shared expert): identity ptok rows 4096..6143.
// ---------------------------------------------------------------------------
__global__ __launch_bounds__(256) void compact_kernel(
    const int* __restrict__ topi, const float* __restrict__ topw, int* __restrict__ segc,
    int* __restrict__ sego, int* __restrict__ ptok, float* __restrict__ pw,
    const float* __restrict__ probs, float* __restrict__ aux_out) {
  __shared__ int c[8];
  __shared__ int off[9];
  __shared__ int cur[8];
  __shared__ float ps[4][8];
  int tid = threadIdx.x;
  if (tid < 8) { c[tid] = 0; cur[tid] = 0; }
  __syncthreads();
  for (int i = tid; i < 4096; i += 256) atomicAdd(&c[topi[i]], 1);
  for (int i = tid; i < 2048; i += 256) ptok[4096 + i] = i;

  float s8[8] = {0.f, 0.f, 0.f, 0.f, 0.f, 0.f, 0.f, 0.f};
  for (int i = tid; i < 2048; i += 256) {
    float4 a = *(const float4*)(probs + i * 8);
    float4 b = *(const float4*)(probs + i * 8 + 4);
    s8[0] += a.x; s8[1] += a.y; s8[2] += a.z; s8[3] += a.w;
    s8[4] += b.x; s8[5] += b.y; s8[6] += b.z; s8[7] += b.w;
  }
#pragma unroll
  for (int e = 0; e < 8; e++) s8[e] = wave_sum64(s8[e]);
  if ((tid & 63) == 0)
#pragma unroll
    for (int e = 0; e < 8; e++) ps[tid >> 6][e] = s8[e];
  __syncthreads();
  if (tid == 0) {
    off[0] = 0;
    for (int e = 0; e < 8; e++) off[e + 1] = off[e] + c[e];
    float a = 0.f;
    for (int e = 0; e < 8; e++) {
      float tot = ps[0][e] + ps[1][e] + ps[2][e] + ps[3][e];
      float d = tot * (1.0f / 2048.0f) - 0.125f;
      a += d * d;
    }
    aux_out[0] = a * (1.0f / 8.0f);
  }
  __syncthreads();
  for (int i = tid; i < 4096; i += 256) {
    int e = topi[i];
    int pidx = atomicAdd(&cur[e], 1);
    int slot = off[e] + pidx;
    ptok[slot] = i >> 1;
    pw[slot] = topw[i];
  }
  if (tid < 8) {
    segc[tid] = c[tid];
    sego[tid] = off[tid];
  }
  if (tid == 0) {
    segc[8] = 2048;
    sego[8] = 4096;
  }
}

// ---------------------------------------------------------------------------
extern "C" void kernel_launch(void* const* d_in, const int* in_sizes, int n_in,
                              void* d_out, int out_size, void* d_ws, size_t ws_size,
                              hipStream_t stream) {
  const float* hidden = (const float*)d_in[0];
  const int* pos_ids = (const int*)d_in[2];
  const float* ln1w = (const float*)d_in[3];
  const float* ln2w = (const float*)d_in[4];
  const float* wq = (const float*)d_in[5];
  const float* wk = (const float*)d_in[6];
  const float* wv = (const float*)d_in[7];
  const float* wo = (const float*)d_in[8];
  const float* router_w = (const float*)d_in[9];
  const float* egw = (const float*)d_in[10];
  const float* euw = (const float*)d_in[11];
  const float* edw = (const float*)d_in[12];
  const float* sgw = (const float*)d_in[13];
  const float* suw = (const float*)d_in[14];
  const float* sdw = (const float*)d_in[15];
  const float* segw = (const float*)d_in[16];
  float* out = (float*)d_out;

  char* p = (char*)d_ws;
  auto alloc = [&](size_t bytes) {
    char* r = p;
    p += (bytes + 255) & ~(size_t)255;
    return r;
  };
  f16* wqkvT = (f16*)alloc(1536l * 1024 * 2);
  f16* woT = (f16*)alloc(1024l * 1024 * 2);
  f16* guT = (f16*)alloc(9l * 2048 * 1024 * 2);   // experts 0-7 + shared(8)
  f16* dnT = (f16*)alloc(9l * 1024 * 1024 * 2);
  f16* xln1 = (f16*)alloc(2048l * 1024 * 2);
  f16* qkv = (f16*)alloc(2048l * 1536 * 2);
  f16* vT = (f16*)alloc(8l * 64 * 1024 * 2);
  f16* attnO = (f16*)alloc(2048l * 1024 * 2);
  float* wo_part = (float*)alloc(2l * 2048 * 1024 * 4);
  f16* x2 = (f16*)alloc(2048l * 1024 * 2);
  f16* act_all = (f16*)alloc(6144l * 1024 * 2);
  int* topi = (int*)alloc(4096 * 4);
  float* topw = (float*)alloc(4096 * 4);
  float* probs = (float*)alloc(2048l * 8 * 4);
  int* ptok = (int*)alloc(6144 * 4);
  float* pwts = (float*)alloc(6144 * 4);
  int* segc = (int*)alloc(9 * 4);
  int* sego = (int*)alloc(9 * 4);

  // ---- attention-path weight transposes, fused with RMSNorm launch ----
  TJobs4 tj4;
  int nj = 0, pre = 0;
  auto addjob4 = [&](const float* s, f16* d, int K, int N) {
    tj4.src[nj] = s; tj4.dst[nj] = d; tj4.K[nj] = K; tj4.N[nj] = N;
    tj4.pre[nj] = pre;
    pre += (N >> 6) * (K >> 6);
    nj++;
  };
  addjob4(wq, wqkvT, 1024, 1024);
  addjob4(wk, wqkvT + 1024l * 1024, 1024, 256);
  addjob4(wv, wqkvT + 1280l * 1024, 1024, 256);
  addjob4(wo, woT, 1024, 1024);
  tj4.pre[nj] = pre;  // sentinel (pre == 640)

  // ---- expert + shared weight transposes, fused with attention launch ----
  TJobs27 tj27;
  int j27 = 0;
  for (int e = 0; e < 8; e++) {
    tj27.src[j27] = egw + (long)e * 1024 * 1024; tj27.dst[j27] = guT + (long)e * 2048 * 1024; j27++;
    tj27.src[j27] = euw + (long)e * 1024 * 1024; tj27.dst[j27] = guT + (long)e * 2048 * 1024 + 1024l * 1024; j27++;
    tj27.src[j27] = edw + (long)e * 1024 * 1024; tj27.dst[j27] = dnT + (long)e * 1024 * 1024; j27++;
  }
  tj27.src[j27] = sgw; tj27.dst[j27] = guT + 8l * 2048 * 1024; j27++;
  tj27.src[j27] = suw; tj27.dst[j27] = guT + 8l * 2048 * 1024 + 1024l * 1024; j27++;
  tj27.src[j27] = sdw; tj27.dst[j27] = dnT + 8l * 1024 * 1024; j27++;

  // attention path (rope fused into QKV epilogue)
  rms_trans_kernel<<<2048 + pre, 256, 0, stream>>>(hidden, ln1w, xln1, tj4);
  gemm_kernel<0, 2, 1><<<dim3(24, 16, 1), 256, 0, stream>>>(xln1, wqkvT, qkv, nullptr, nullptr, nullptr, nullptr, pos_ids, 1536, 1024, 0);
  vtrans_kernel<<<dim3(8, 16, 1), 256, 0, stream>>>(qkv, vT);
  attn_trans_kernel<<<512 + 27 * 128, 256, 0, stream>>>(qkv, vT, attnO, tj27);
  // WO: K-split x2 into f32 partials; rms2r combines into OUT(resid) + x2 + router
  gemm_kernel<2, 2, 0><<<dim3(16, 16, 2), 256, 0, stream>>>(attnO, woT, wo_part, nullptr, nullptr, nullptr, nullptr, nullptr, 1024, 1024, 2048l * 1024);
  rms2r_kernel<<<2048, 256, 0, stream>>>(hidden, wo_part, wo_part + 2048l * 1024, ln2w, router_w, segw, out, x2, topi, topw, probs, pwts + 4096);

  // MoE path (shared expert = segment 8; its pw = sgate from router)
  compact_kernel<<<1, 256, 0, stream>>>(topi, topw, segc, sego, ptok, pwts, probs, out + 2097152);

  // flattened worklists: y = m-tile index (0..15 shared-first, 16..55 routed)
  gemm_kernel<5, 4, 0><<<dim3(16, 56, 1), 256, 0, stream>>>(x2, guT, act_all, ptok, nullptr, segc, sego, nullptr, 1024, 1024, 2048l * 1024);
  gemm_kernel<6, 2, 0><<<dim3(16, 56, 1), 256, 0, stream>>>(act_all, dnT, out, ptok, pwts, segc, sego, nullptr, 1024, 1024, 1024l * 1024);
}

// Round 3
// 330.667 us; speedup vs baseline: 1.1471x; 1.0456x over previous
//
#include <hip/hip_runtime.h>
#include <cstdint>
#include <cstddef>

typedef _Float16 f16;
typedef _Float16 f16x8 __attribute__((ext_vector_type(8)));
typedef float f32x4 __attribute__((ext_vector_type(4)));

#define SEQ 1024

// ---------------------------------------------------------------------------
// helpers
// ---------------------------------------------------------------------------
__device__ __forceinline__ float wave_sum64(float v) {
#pragma unroll
  for (int m = 1; m < 64; m <<= 1) v += __shfl_xor(v, m);
  return v;
}

// ---------------------------------------------------------------------------
// fused: RMSNorm (blocks 0..2047) + attention-weight transpose (blocks 2048+)
// transpose: f32 [K,N] -> f16 [N,K], 64x64 tiles (wq/wk/wv/wo only).
// ---------------------------------------------------------------------------
struct TJobs4 {
  const float* src[4];
  f16* dst[4];
  int K[4], N[4];
  int pre[5];
};

__global__ __launch_bounds__(256) void rms_trans_kernel(
    const float* __restrict__ x, const float* __restrict__ w,
    f16* __restrict__ out, TJobs4 a) {
  __shared__ float tile[64][65];
  __shared__ float sred[4];
  int tid = threadIdx.x;
  int bid = blockIdx.x;
  if (bid >= 2048) {
    int t = bid - 2048;
    int job = 0;
    while (job < 3 && t >= a.pre[job + 1]) job++;
    t -= a.pre[job];
    const float* src = a.src[job];
    f16* dst = a.dst[job];
    int K = a.K[job], N = a.N[job];
    int ntn = N >> 6;
    int n0 = (t % ntn) * 64;
    int k0 = (t / ntn) * 64;
#pragma unroll
    for (int i = 0; i < 4; i++) {
      int c = i * 256 + tid;
      int kr = c >> 4, cc = c & 15;
      float4 v = *(const float4*)(src + (long)(k0 + kr) * N + n0 + cc * 4);
      tile[kr][cc * 4 + 0] = v.x;
      tile[kr][cc * 4 + 1] = v.y;
      tile[kr][cc * 4 + 2] = v.z;
      tile[kr][cc * 4 + 3] = v.w;
    }
    __syncthreads();
#pragma unroll
    for (int i = 0; i < 2; i++) {
      int c = i * 256 + tid;
      int nr = c >> 3, kc = (c & 7) * 8;
      union { f16 h[8]; uint4 u; } cv;
#pragma unroll
      for (int jj = 0; jj < 8; jj++) cv.h[jj] = (f16)tile[kc + jj][nr];
      *(uint4*)(dst + (long)(n0 + nr) * K + k0 + kc) = cv.u;
    }
    return;
  }
  long t = bid;
  float4 v = ((const float4*)(x + t * 1024))[tid];
  float ss = v.x * v.x + v.y * v.y + v.z * v.z + v.w * v.w;
  ss = wave_sum64(ss);
  if ((tid & 63) == 0) sred[tid >> 6] = ss;
  __syncthreads();
  float tot = sred[0] + sred[1] + sred[2] + sred[3];
  float sc = rsqrtf(tot * (1.0f / 1024.0f) + 1e-6f);
  float4 wv = ((const float4*)w)[tid];
  union { f16 h[4]; uint2 u; } cv;
  cv.h[0] = (f16)(v.x * wv.x * sc);
  cv.h[1] = (f16)(v.y * wv.y * sc);
  cv.h[2] = (f16)(v.z * wv.z * sc);
  cv.h[3] = (f16)(v.w * wv.w * sc);
  *(uint2*)(out + t * 1024 + tid * 4) = cv.u;
}

// ---------------------------------------------------------------------------
// fused: resid = hidden + P1 + P2 -> OUT(f32); x2 = rms(resid)*w (f16);
// ALSO router: logits = xn . rw -> softmax -> top2/probs; sgate -> pw_shared.
// ---------------------------------------------------------------------------
__global__ __launch_bounds__(256) void rms2r_kernel(
    const float* __restrict__ hidden, const float* __restrict__ p1,
    const float* __restrict__ p2, const float* __restrict__ w,
    const float* __restrict__ rw, const float* __restrict__ segw,
    float* __restrict__ out_resid, f16* __restrict__ x2out,
    int* __restrict__ topi, float* __restrict__ topw,
    float* __restrict__ probs, float* __restrict__ pw_shared) {
  long t = blockIdx.x;
  int tid = threadIdx.x;
  float4 h = ((const float4*)(hidden + t * 1024))[tid];
  float4 a = ((const float4*)(p1 + t * 1024))[tid];
  float4 b = ((const float4*)(p2 + t * 1024))[tid];
  float4 v;
  v.x = h.x + a.x + b.x;
  v.y = h.y + a.y + b.y;
  v.z = h.z + a.z + b.z;
  v.w = h.w + a.w + b.w;
  ((float4*)(out_resid + t * 1024))[tid] = v;
  float ss = v.x * v.x + v.y * v.y + v.z * v.z + v.w * v.w;
  ss = wave_sum64(ss);
  __shared__ float sred[4];
  if ((tid & 63) == 0) sred[tid >> 6] = ss;
  __syncthreads();
  float tot = sred[0] + sred[1] + sred[2] + sred[3];
  float sc = rsqrtf(tot * (1.0f / 1024.0f) + 1e-6f);
  float4 wv = ((const float4*)w)[tid];
  float xa[4];
  xa[0] = v.x * wv.x * sc;
  xa[1] = v.y * wv.y * sc;
  xa[2] = v.z * wv.z * sc;
  xa[3] = v.w * wv.w * sc;
  union { f16 h[4]; uint2 u; } cv;
#pragma unroll
  for (int k = 0; k < 4; k++) cv.h[k] = (f16)xa[k];
  *(uint2*)(x2out + t * 1024 + tid * 4) = cv.u;

  // router logits
  float lacc[8] = {0.f, 0.f, 0.f, 0.f, 0.f, 0.f, 0.f, 0.f};
#pragma unroll
  for (int k = 0; k < 4; k++) {
    const float4* r4 = (const float4*)(rw + (tid * 4 + k) * 8);
    float4 ra = r4[0], rb = r4[1];
    float xk = xa[k];
    lacc[0] += xk * ra.x; lacc[1] += xk * ra.y; lacc[2] += xk * ra.z; lacc[3] += xk * ra.w;
    lacc[4] += xk * rb.x; lacc[5] += xk * rb.y; lacc[6] += xk * rb.z; lacc[7] += xk * rb.w;
  }
  float4 sg4 = ((const float4*)segw)[tid];
  float l9 = xa[0] * sg4.x + xa[1] * sg4.y + xa[2] * sg4.z + xa[3] * sg4.w;
#pragma unroll
  for (int m = 1; m < 64; m <<= 1) {
#pragma unroll
    for (int e = 0; e < 8; e++) lacc[e] += __shfl_xor(lacc[e], m);
    l9 += __shfl_xor(l9, m);
  }
  __shared__ float red[4][9];
  if ((tid & 63) == 0) {
#pragma unroll
    for (int e = 0; e < 8; e++) red[tid >> 6][e] = lacc[e];
    red[tid >> 6][8] = l9;
  }
  __syncthreads();
  if (tid == 0) {
    float p[8];
    float mx = -1e30f;
#pragma unroll
    for (int e = 0; e < 8; e++) {
      p[e] = red[0][e] + red[1][e] + red[2][e] + red[3][e];
      mx = fmaxf(mx, p[e]);
    }
    float l9t = red[0][8] + red[1][8] + red[2][8] + red[3][8];
    pw_shared[t] = 1.0f / (1.0f + expf(-l9t));
    float s = 0.f;
#pragma unroll
    for (int e = 0; e < 8; e++) {
      p[e] = expf(p[e] - mx);
      s += p[e];
    }
    float inv = 1.0f / s;
#pragma unroll
    for (int e = 0; e < 8; e++) p[e] *= inv;
    float4 pa = {p[0], p[1], p[2], p[3]};
    float4 pb = {p[4], p[5], p[6], p[7]};
    *(float4*)(probs + t * 8) = pa;
    *(float4*)(probs + t * 8 + 4) = pb;
    int i1 = 0;
    float b1 = p[0];
#pragma unroll
    for (int e = 1; e < 8; e++)
      if (p[e] > b1) { b1 = p[e]; i1 = e; }
    int i2 = -1;
    float b2 = -1.f;
#pragma unroll
    for (int e = 0; e < 8; e++)
      if (e != i1 && p[e] > b2) { b2 = p[e]; i2 = e; }
    topi[2 * t] = i1;
    topi[2 * t + 1] = i2;
    topw[2 * t] = b1;
    topw[2 * t + 1] = b2;
  }
}

// ---------------------------------------------------------------------------
// GEMM: C[M,N] = A[M,K] * BT[N,K]^T  (f16 in, f32 acc, MFMA 16x16x32)
// 256 threads (4 waves, 2x2), tile 128 x (32*TN), BK=64,
// DOUBLE-BUFFERED global_load_lds(16B) staging with XOR-swizzled placement.
// MODE 0: dense, f16 out; ROPE=1 applies rotary to cols < 1280 during store.
// MODE 2: dense, f32 out, K-split via blockIdx.z (out += z*estride)
// MODE 5: moe, flattened worklist over blockIdx.y (shared expert first);
//         B = 64 gate + 64 up rows; epilogue act = silu(g)*u (TN must be 4)
// MODE 7: moe, flattened worklist; A rows direct; epilogue plain f32 stores
//         to y[(poff+row)*N + col] (no atomics; combine kernel sums later)
// ---------------------------------------------------------------------------
template <int MODE, int TN, int ROPE>
__global__ __launch_bounds__(256) void gemm_kernel(
    const f16* __restrict__ A, const f16* __restrict__ BT, void* __restrict__ outp,
    const int* __restrict__ ptok, const float* __restrict__ pw,
    const int* __restrict__ segc, const int* __restrict__ sego,
    const int* __restrict__ pos_ids, int N, int K, long estride) {
  const int tile_n = 32 * TN;
  int n0 = blockIdx.x * tile_n;
  int a0 = blockIdx.x * 64;  // MODE5 act-col base
  int m0 = blockIdx.y * 128;
  int cnt = 1 << 30, poff = 0;
  int kbeg = 0, klen = K;
  float* po = (float*)outp;
  if (MODE >= 5) {
    // flattened worklist: mt 0..15 -> shared expert (seg 8), dispatched first;
    // mt 16+ -> routed expert m-tiles packed in expert order.
    int mt = blockIdx.y;
    int e, lm;
    if (mt < 16) {
      e = 8; lm = mt;
    } else {
      int r = mt - 16;
      e = 0;
      while (e < 8) {
        int nt = (segc[e] + 127) >> 7;
        if (r < nt) break;
        r -= nt;
        e++;
      }
      if (e == 8) return;
      lm = r;
    }
    cnt = segc[e];
    poff = sego[e];
    m0 = lm * 128;
    if (cnt == 0 || m0 >= cnt) return;
    BT += (long)e * estride;
  } else if (MODE == 2) {
    klen = K / gridDim.z;
    kbeg = blockIdx.z * klen;
    po += (long)blockIdx.z * estride;
  }
  constexpr int STAGE = 8192 + 2048 * TN;  // f16 elems per buffer
  constexpr int EPI = (MODE == 0 || MODE == 5) ? 128 * 32 * TN : 0;
  constexpr int DBUF = 2 * STAGE;
  constexpr int SMEMN = DBUF > EPI ? DBUF : EPI;
  __shared__ f16 smem[SMEMN];
  int tid = threadIdx.x;
  int w = tid >> 6, lane = tid & 63;
  int quad = lane >> 4, l16 = lane & 15;
  int wm = (w >> 1) * 64, wn = (w & 1) * (TN * 16);

  const f16* agp[4];
  const f16* bgp[TN];
#pragma unroll
  for (int i = 0; i < 4; i++) {
    int c = i * 256 + tid;
    int r = c >> 3;
    int kq = (c & 7) ^ (r & 7);
    int ar = m0 + r;
    if (MODE == 5) {
      int rr = ar < cnt ? ar : cnt - 1;
      agp[i] = A + (long)ptok[poff + rr] * K + kq * 8;
    } else if (MODE == 7) {
      int rr = ar < cnt ? ar : cnt - 1;
      agp[i] = A + (long)(poff + rr) * K + kq * 8;
    } else {
      agp[i] = A + (long)ar * K + kq * 8;
    }
  }
#pragma unroll
  for (int i = 0; i < TN; i++) {
    int c = i * 256 + tid;
    int r = c >> 3;
    int kq = (c & 7) ^ (r & 7);
    long br;
    if (MODE == 5) br = (r < 64) ? (a0 + r) : (1024 + a0 + (r - 64));
    else br = n0 + r;
    bgp[i] = BT + br * K + kq * 8;
  }

  auto stage = [&](int kk0, int buf) {
    f16* dstA = smem + buf * STAGE;
    f16* dstB = dstA + 8192;
#pragma unroll
    for (int i = 0; i < 4; i++)
      __builtin_amdgcn_global_load_lds(
          (const __attribute__((address_space(1))) void*)(agp[i] + kk0),
          (__attribute__((address_space(3))) void*)(dstA + (i * 256 + w * 64) * 8),
          16, 0, 0);
#pragma unroll
    for (int i = 0; i < TN; i++)
      __builtin_amdgcn_global_load_lds(
          (const __attribute__((address_space(1))) void*)(bgp[i] + kk0),
          (__attribute__((address_space(3))) void*)(dstB + (i * 256 + w * 64) * 8),
          16, 0, 0);
  };

  f32x4 acc[4][TN] = {};

  stage(kbeg, 0);
  __syncthreads();  // drains vmcnt(0): buf0 ready
  int cur = 0;
  for (int k0 = kbeg; k0 < kbeg + klen; k0 += 64) {
    if (k0 + 64 < kbeg + klen) stage(k0 + 64, cur ^ 1);  // prefetch next tile
    const f16* As = smem + cur * STAGE;
    const f16* Bs = As + 8192;
#pragma unroll
    for (int kk = 0; kk < 2; kk++) {
      f16x8 af[4], bf[TN];
      int q = kk * 4 + quad;
#pragma unroll
      for (int i = 0; i < 4; i++) {
        int ra = wm + i * 16 + l16;
        af[i] = *(const f16x8*)&As[ra * 64 + (q ^ (ra & 7)) * 8];
      }
#pragma unroll
      for (int j = 0; j < TN; j++) {
        int rb = wn + j * 16 + l16;
        bf[j] = *(const f16x8*)&Bs[rb * 64 + (q ^ (rb & 7)) * 8];
      }
#pragma unroll
      for (int i = 0; i < 4; i++)
#pragma unroll
        for (int j = 0; j < TN; j++)
          acc[i][j] = __builtin_amdgcn_mfma_f32_16x16x32_f16(af[i], bf[j], acc[i][j], 0, 0, 0);
    }
    __syncthreads();  // drains vmcnt(0): next buf ready, this buf free
    cur ^= 1;
  }

  if (MODE == 2) {
#pragma unroll
    for (int i = 0; i < 4; i++)
#pragma unroll
      for (int j = 0; j < TN; j++) {
        int col = n0 + wn + j * 16 + l16;
#pragma unroll
        for (int r = 0; r < 4; r++) {
          int row = m0 + wm + i * 16 + quad * 4 + r;
          po[(long)row * N + col] = acc[i][j][r];
        }
      }
  } else if (MODE == 7) {
#pragma unroll
    for (int i = 0; i < 4; i++)
#pragma unroll
      for (int j = 0; j < TN; j++) {
        int col = n0 + wn + j * 16 + l16;
#pragma unroll
        for (int r = 0; r < 4; r++) {
          int row = m0 + wm + i * 16 + quad * 4 + r;
          if (row < cnt) po[(long)(poff + row) * N + col] = acc[i][j][r];
        }
      }
  } else {
    // epilogue via LDS with chunk-XOR swizzle (chunk' = chunk ^ (row&7))
    __syncthreads();
#pragma unroll
    for (int i = 0; i < 4; i++)
#pragma unroll
      for (int j = 0; j < TN; j++)
#pragma unroll
        for (int r = 0; r < 4; r++) {
          int lr = wm + i * 16 + quad * 4 + r;
          int lc = wn + j * 16 + l16;
          int sc_ = ((((lc >> 3) ^ (lr & 7)) << 3) | (lc & 7));
          smem[lr * tile_n + sc_] = (f16)acc[i][j][r];
        }
    __syncthreads();
    if (MODE == 5) {
      // act = silu(gate)*up : gate chunks 0..7, up chunks 8..15 per row
#pragma unroll
      for (int ii = 0; ii < 4; ii++) {
        int c = ii * 256 + tid;
        int row = c >> 3, ci = c & 7;
        int grow = m0 + row;
        if (grow < cnt) {
          int gci = ci ^ (row & 7);
          f16x8 gv = *(const f16x8*)&smem[row * 128 + gci * 8];
          f16x8 uv = *(const f16x8*)&smem[row * 128 + (gci + 8) * 8];
          union { uint4 u; f16 h[8]; } ov;
#pragma unroll
          for (int jj = 0; jj < 8; jj++) {
            float g = (float)gv[jj];
            float u = (float)uv[jj];
            ov.h[jj] = (f16)(g / (1.0f + __expf(-g)) * u);
          }
          *(uint4*)&((f16*)outp)[(long)(poff + grow) * N + a0 + ci * 8] = ov.u;
        }
      }
    } else {
      const int cpr = tile_n / 8;
#pragma unroll
      for (int ii = 0; ii < 2 * TN; ii++) {
        int c = ii * 256 + tid;
        int row = c / cpr, ci = c % cpr;
        int off = ci * 8;
        int grow = m0 + row;
        union { uint4 u; f16 h[8]; } sv;
        sv.u = *(const uint4*)&smem[row * tile_n + (ci ^ (row & 7)) * 8];
        if (ROPE && n0 < 1280) {
          union { uint4 u; f16 h[8]; } pv;
          pv.u = *(const uint4*)&smem[row * tile_n + ((ci ^ 4) ^ (row & 7)) * 8];
          int pos = pos_ids[grow];
          bool low = off < 32;
#pragma unroll
          for (int jj = 0; jj < 8; jj++) {
            int fi = (off & 31) + jj;
            float fr = (float)pos * __expf((float)fi * (-13.815510557964274f / 32.0f));
            float sn, cs;
            sincosf(fr, &sn, &cs);
            float x = (float)sv.h[jj], y = (float)pv.h[jj];
            sv.h[jj] = (f16)(low ? (x * cs - y * sn) : (x * cs + y * sn));
          }
        }
        *(uint4*)&((f16*)outp)[(long)grow * N + n0 + off] = sv.u;
      }
    }
  }
}

// ---------------------------------------------------------------------------
// combine: out[t] += pw[s1]*y[s1] + pw[s2]*y[s2] + pw[4096+t]*y[4096+t]
// (out already holds resid from rms2r)
// ---------------------------------------------------------------------------
__global__ __launch_bounds__(256) void combine_kernel(
    const float* __restrict__ y, const int* __restrict__ tslot,
    const float* __restrict__ pw, float* __restrict__ out) {
  long t = blockIdx.x;
  int tid = threadIdx.x;
  int s1 = tslot[2 * t], s2 = tslot[2 * t + 1];
  float w1 = pw[s1], w2 = pw[s2], ws = pw[4096 + t];
  float4 a = ((const float4*)(y + (long)s1 * 1024))[tid];
  float4 b = ((const float4*)(y + (long)s2 * 1024))[tid];
  float4 c = ((const float4*)(y + (long)(4096 + t) * 1024))[tid];
  float4 o = ((const float4*)(out + t * 1024))[tid];
  o.x += w1 * a.x + w2 * b.x + ws * c.x;
  o.y += w1 * a.y + w2 * b.y + ws * c.y;
  o.z += w1 * a.z + w2 * b.z + ws * c.z;
  o.w += w1 * a.w + w2 * b.w + ws * c.w;
  ((float4*)(out + t * 1024))[tid] = o;
}

// ---------------------------------------------------------------------------
// V transpose: qkv v-section -> vT [B*NKV][64 d][1024 seq]
// ---------------------------------------------------------------------------
__global__ __launch_bounds__(256) void vtrans_kernel(const f16* __restrict__ qkv,
                                                     f16* __restrict__ vT) {
  int bk = blockIdx.x;
  int st = blockIdx.y;
  int b = bk >> 2, kvh = bk & 3;
  int s0 = st * 64;
  int tid = threadIdx.x;
#pragma unroll
  for (int i = 0; i < 2; i++) {
    int c = i * 256 + tid;
    int d = c & 63, sc = c >> 6;
    union { uint4 u; f16 h[8]; } v;
#pragma unroll
    for (int j = 0; j < 8; j++)
      v.h[j] = qkv[(long)(b * SEQ + s0 + sc * 8 + j) * 1536 + 1280 + kvh * 64 + d];
    *(uint4*)&vT[((long)bk * 64 + d) * 1024 + s0 + sc * 8] = v.u;
  }
}

// ---------------------------------------------------------------------------
// MFMA flash attention (blocks 0..511) FUSED with expert/shared weight
// transpose (blocks 512+). Transpose: f32 [1024,1024] -> f16 [1024,1024]^T,
// 128k x 64n region per block, LDS tile [128][65] f32 aliased onto attn smem.
// ---------------------------------------------------------------------------
struct TJobs27 {
  const float* src[27];
  f16* dst[27];
};

__global__ __launch_bounds__(256) void attn_trans_kernel(
    const f16* __restrict__ qkv, const f16* __restrict__ vT,
    f16* __restrict__ aout, TJobs27 tj) {
  __shared__ f16 smem[24576];  // Qs[64][64] | Ks[128][64] | Vs[64][128] | Ps 4x1024
  int tid = threadIdx.x;
  int bid = blockIdx.x;

  if (bid >= 512) {
    // ---- transpose path ----
    int t = bid - 512;
    int job = t >> 7;          // 128 blocks per 1024x1024 job
    int tt = t & 127;
    int n0 = (tt & 15) << 6;   // 16 n-tiles of 64
    int k0 = (tt >> 4) << 7;   // 8 k-tiles of 128
    const float* src = tj.src[job];
    f16* dst = tj.dst[job];
    float* tile = (float*)smem;  // [128][65] = 33280B
#pragma unroll
    for (int i = 0; i < 8; i++) {
      int c = i * 256 + tid;
      int kr = c >> 4, cc = c & 15;
      float4 v = *(const float4*)(src + (long)(k0 + kr) * 1024 + n0 + cc * 4);
      tile[kr * 65 + cc * 4 + 0] = v.x;
      tile[kr * 65 + cc * 4 + 1] = v.y;
      tile[kr * 65 + cc * 4 + 2] = v.z;
      tile[kr * 65 + cc * 4 + 3] = v.w;
    }
    __syncthreads();
#pragma unroll
    for (int i = 0; i < 4; i++) {
      int c = i * 256 + tid;
      int nr = c >> 4, kc = c & 15;
      union { f16 h[8]; uint4 u; } cv;
#pragma unroll
      for (int jj = 0; jj < 8; jj++) cv.h[jj] = (f16)tile[(kc * 8 + jj) * 65 + nr];
      *(uint4*)(dst + (long)(n0 + nr) * 1024 + k0 + kc * 8) = cv.u;
    }
    return;
  }

  // ---- attention path ----
  int bh = bid & 31;
  int b = bh >> 4, h = bh & 15;
  int kvh = h >> 2;
  int qt = bid >> 5;
  int q0 = qt * 64;
  int w = tid >> 6, lane = tid & 63;
  int quad = lane >> 4, l16 = lane & 15;

  f16* Qs = smem;
  f16* Ks = smem + 4096;
  f16* Vs = smem + 12288;
  f16* Psw = smem + 20480 + w * 1024;

#pragma unroll
  for (int i = 0; i < 2; i++) {
    int c = i * 256 + tid;
    int r = c >> 3;
    int kq = (c & 7) ^ (r & 7);
    __builtin_amdgcn_global_load_lds(
        (const __attribute__((address_space(1))) void*)(qkv + (long)(b * SEQ + q0 + r) * 1536 + h * 64 + kq * 8),
        (__attribute__((address_space(3))) void*)(Qs + c * 8), 16, 0, 0);
  }

  float mr[4], lsum[4];
  f32x4 oacc[4] = {};
#pragma unroll
  for (int r = 0; r < 4; r++) { mr[r] = -1e30f; lsum[r] = 0.f; }

  int nch = (qt + 2) >> 1;
  for (int ch = 0; ch < nch; ch++) {
    __syncthreads();
#pragma unroll
    for (int i = 0; i < 4; i++) {
      int c = i * 256 + tid;
      int r = c >> 3;
      int kq = (c & 7) ^ (r & 7);
      __builtin_amdgcn_global_load_lds(
          (const __attribute__((address_space(1))) void*)(qkv + (long)(b * SEQ + ch * 128 + r) * 1536 + 1024 + kvh * 64 + kq * 8),
          (__attribute__((address_space(3))) void*)(Ks + c * 8), 16, 0, 0);
    }
#pragma unroll
    for (int i = 0; i < 4; i++) {
      int c = i * 256 + tid;
      int d = c >> 4;
      int kq = (c & 15) ^ (d & 15);
      __builtin_amdgcn_global_load_lds(
          (const __attribute__((address_space(1))) void*)(vT + ((long)(b * 4 + kvh) * 64 + d) * 1024 + ch * 128 + kq * 8),
          (__attribute__((address_space(3))) void*)(Vs + c * 8), 16, 0, 0);
    }
    __syncthreads();

    for (int half = 0; half < 2; half++) {
      int kt = ch * 2 + half;
      if (kt > qt) break;

      int m = w * 16 + l16;
      f16x8 aq0 = *(const f16x8*)&Qs[m * 64 + ((quad) ^ (m & 7)) * 8];
      f16x8 aq1 = *(const f16x8*)&Qs[m * 64 + ((4 + quad) ^ (m & 7)) * 8];
      f32x4 sacc[4];
#pragma unroll
      for (int j = 0; j < 4; j++) {
        int n = half * 64 + j * 16 + l16;
        f16x8 bk0 = *(const f16x8*)&Ks[n * 64 + ((quad) ^ (n & 7)) * 8];
        f16x8 bk1 = *(const f16x8*)&Ks[n * 64 + ((4 + quad) ^ (n & 7)) * 8];
        f32x4 z = {};
        z = __builtin_amdgcn_mfma_f32_16x16x32_f16(aq0, bk0, z, 0, 0, 0);
        z = __builtin_amdgcn_mfma_f32_16x16x32_f16(aq1, bk1, z, 0, 0, 0);
        sacc[j] = z;
      }

      bool diag = (kt == qt);
      float sv[4][4];
      float rowmax[4];
#pragma unroll
      for (int r = 0; r < 4; r++) rowmax[r] = -1e30f;
#pragma unroll
      for (int j = 0; j < 4; j++)
#pragma unroll
        for (int r = 0; r < 4; r++) {
          float s = sacc[j][r] * 0.125f;
          if (diag && (j * 16 + l16 > w * 16 + quad * 4 + r)) s = -1e30f;
          sv[j][r] = s;
          rowmax[r] = fmaxf(rowmax[r], s);
        }
#pragma unroll
      for (int r = 0; r < 4; r++) {
        rowmax[r] = fmaxf(rowmax[r], __shfl_xor(rowmax[r], 1));
        rowmax[r] = fmaxf(rowmax[r], __shfl_xor(rowmax[r], 2));
        rowmax[r] = fmaxf(rowmax[r], __shfl_xor(rowmax[r], 4));
        rowmax[r] = fmaxf(rowmax[r], __shfl_xor(rowmax[r], 8));
      }
#pragma unroll
      for (int r = 0; r < 4; r++) {
        float mn = fmaxf(mr[r], rowmax[r]);
        float al = __expf(mr[r] - mn);
        mr[r] = mn;
        float rs = 0.f;
#pragma unroll
        for (int j = 0; j < 4; j++) {
          float pv = __expf(sv[j][r] - mn);
          sv[j][r] = pv;
          rs += pv;
        }
        rs += __shfl_xor(rs, 1);
        rs += __shfl_xor(rs, 2);
        rs += __shfl_xor(rs, 4);
        rs += __shfl_xor(rs, 8);
        lsum[r] = lsum[r] * al + rs;
#pragma unroll
        for (int j = 0; j < 4; j++) oacc[j][r] *= al;
      }

#pragma unroll
      for (int j = 0; j < 4; j++)
#pragma unroll
        for (int r = 0; r < 4; r++) {
          int row = quad * 4 + r;
          int chunk = j * 2 + (l16 >> 3);
          Psw[row * 64 + (chunk ^ (row & 7)) * 8 + (l16 & 7)] = (f16)sv[j][r];
        }

      f16x8 pf0 = *(const f16x8*)&Psw[l16 * 64 + ((quad) ^ (l16 & 7)) * 8];
      f16x8 pf1 = *(const f16x8*)&Psw[l16 * 64 + ((4 + quad) ^ (l16 & 7)) * 8];
#pragma unroll
      for (int j = 0; j < 4; j++) {
        int d = j * 16 + l16;
        f16x8 v0 = *(const f16x8*)&Vs[d * 128 + (((half * 8 + quad) ^ (d & 15))) * 8];
        f16x8 v1 = *(const f16x8*)&Vs[d * 128 + (((half * 8 + 4 + quad) ^ (d & 15))) * 8];
        oacc[j] = __builtin_amdgcn_mfma_f32_16x16x32_f16(pf0, v0, oacc[j], 0, 0, 0);
        oacc[j] = __builtin_amdgcn_mfma_f32_16x16x32_f16(pf1, v1, oacc[j], 0, 0, 0);
      }
    }
  }

  __syncthreads();
  f16* Os = smem;
  float iv[4];
#pragma unroll
  for (int r = 0; r < 4; r++) iv[r] = 1.0f / lsum[r];
#pragma unroll
  for (int j = 0; j < 4; j++)
#pragma unroll
    for (int r = 0; r < 4; r++)
      Os[(w * 16 + quad * 4 + r) * 72 + j * 16 + l16] = (f16)(oacc[j][r] * iv[r]);
  __syncthreads();
#pragma unroll
  for (int i = 0; i < 2; i++) {
    int c = i * 256 + tid;
    int row = c >> 3, off = (c & 7) * 8;
    uint4 v = *(const uint4*)&Os[row * 72 + off];
    *(uint4*)&aout[(long)(b * SEQ + q0 + row) * 1024 + h * 64 + off] = v;
  }
}

// ---------------------------------------------------------------------------
// compact pairs by expert (single block) + psum reduction + aux output.
// Fills segment 8 (shared expert): identity ptok rows 4096..6143.
// Also emits tslot[i] = slot for pair i (inverse map for combine).
// ---------------------------------------------------------------------------
__global__ __launch_bounds__(256) void compact_kernel(
    const int* __restrict__ topi, const float* __restrict__ topw, int* __restrict__ segc,
    int* __restrict__ sego, int* __restrict__ ptok, float* __restrict__ pw,
    const float* __restrict__ probs, float* __restrict__ aux_out,
    int* __restrict__ tslot) {
  __shared__ int c[8];
  __shared__ int off[9];
  __shared__ int cur[8];
  __shared__ float ps[4][8];
  int tid = threadIdx.x;
  if (tid < 8) { c[tid] = 0; cur[tid] = 0; }
  __syncthreads();
  for (int i = tid; i < 4096; i += 256) atomicAdd(&c[topi[i]], 1);
  for (int i = tid; i < 2048; i += 256) ptok[4096 + i] = i;

  float s8[8] = {0.f, 0.f, 0.f, 0.f, 0.f, 0.f, 0.f, 0.f};
  for (int i = tid; i < 2048; i += 256) {
    float4 a = *(const float4*)(probs + i * 8);
    float4 b = *(const float4*)(probs + i * 8 + 4);
    s8[0] += a.x; s8[1] += a.y; s8[2] += a.z; s8[3] += a.w;
    s8[4] += b.x; s8[5] += b.y; s8[6] += b.z; s8[7] += b.w;
  }
#pragma unroll
  for (int e = 0; e < 8; e++) s8[e] = wave_sum64(s8[e]);
  if ((tid & 63) == 0)
#pragma unroll
    for (int e = 0; e < 8; e++) ps[tid >> 6][e] = s8[e];
  __syncthreads();
  if (tid == 0) {
    off[0] = 0;
    for (int e = 0; e < 8; e++) off[e + 1] = off[e] + c[e];
    float a = 0.f;
    for (int e = 0; e < 8; e++) {
      float tot = ps[0][e] + ps[1][e] + ps[2][e] + ps[3][e];
      float d = tot * (1.0f / 2048.0f) - 0.125f;
      a += d * d;
    }
    aux_out[0] = a * (1.0f / 8.0f);
  }
  __syncthreads();
  for (int i = tid; i < 4096; i += 256) {
    int e = topi[i];
    int pidx = atomicAdd(&cur[e], 1);
    int slot = off[e] + pidx;
    ptok[slot] = i >> 1;
    pw[slot] = topw[i];
    tslot[i] = slot;
  }
  if (tid < 8) {
    segc[tid] = c[tid];
    sego[tid] = off[tid];
  }
  if (tid == 0) {
    segc[8] = 2048;
    sego[8] = 4096;
  }
}

// ---------------------------------------------------------------------------
extern "C" void kernel_launch(void* const* d_in, const int* in_sizes, int n_in,
                              void* d_out, int out_size, void* d_ws, size_t ws_size,
                              hipStream_t stream) {
  const float* hidden = (const float*)d_in[0];
  const int* pos_ids = (const int*)d_in[2];
  const float* ln1w = (const float*)d_in[3];
  const float* ln2w = (const float*)d_in[4];
  const float* wq = (const float*)d_in[5];
  const float* wk = (const float*)d_in[6];
  const float* wv = (const float*)d_in[7];
  const float* wo = (const float*)d_in[8];
  const float* router_w = (const float*)d_in[9];
  const float* egw = (const float*)d_in[10];
  const float* euw = (const float*)d_in[11];
  const float* edw = (const float*)d_in[12];
  const float* sgw = (const float*)d_in[13];
  const float* suw = (const float*)d_in[14];
  const float* sdw = (const float*)d_in[15];
  const float* segw = (const float*)d_in[16];
  float* out = (float*)d_out;

  char* p = (char*)d_ws;
  auto alloc = [&](size_t bytes) {
    char* r = p;
    p += (bytes + 255) & ~(size_t)255;
    return r;
  };
  f16* wqkvT = (f16*)alloc(1536l * 1024 * 2);
  f16* woT = (f16*)alloc(1024l * 1024 * 2);
  f16* guT = (f16*)alloc(9l * 2048 * 1024 * 2);   // experts 0-7 + shared(8)
  f16* dnT = (f16*)alloc(9l * 1024 * 1024 * 2);
  f16* xln1 = (f16*)alloc(2048l * 1024 * 2);
  f16* qkv = (f16*)alloc(2048l * 1536 * 2);
  f16* vT = (f16*)alloc(8l * 64 * 1024 * 2);
  f16* attnO = (f16*)alloc(2048l * 1024 * 2);
  float* wo_part = (float*)alloc(2l * 2048 * 1024 * 4);
  f16* x2 = (f16*)alloc(2048l * 1024 * 2);
  f16* act_all = (f16*)alloc(6144l * 1024 * 2);
  float* y_all = (float*)alloc(6144l * 1024 * 4);
  int* topi = (int*)alloc(4096 * 4);
  float* topw = (float*)alloc(4096 * 4);
  float* probs = (float*)alloc(2048l * 8 * 4);
  int* ptok = (int*)alloc(6144 * 4);
  float* pwts = (float*)alloc(6144 * 4);
  int* tslot = (int*)alloc(4096 * 4);
  int* segc = (int*)alloc(9 * 4);
  int* sego = (int*)alloc(9 * 4);

  // ---- attention-path weight transposes, fused with RMSNorm launch ----
  TJobs4 tj4;
  int nj = 0, pre = 0;
  auto addjob4 = [&](const float* s, f16* d, int K, int N) {
    tj4.src[nj] = s; tj4.dst[nj] = d; tj4.K[nj] = K; tj4.N[nj] = N;
    tj4.pre[nj] = pre;
    pre += (N >> 6) * (K >> 6);
    nj++;
  };
  addjob4(wq, wqkvT, 1024, 1024);
  addjob4(wk, wqkvT + 1024l * 1024, 1024, 256);
  addjob4(wv, wqkvT + 1280l * 1024, 1024, 256);
  addjob4(wo, woT, 1024, 1024);
  tj4.pre[nj] = pre;  // sentinel (pre == 640)

  // ---- expert + shared weight transposes, fused with attention launch ----
  TJobs27 tj27;
  int j27 = 0;
  for (int e = 0; e < 8; e++) {
    tj27.src[j27] = egw + (long)e * 1024 * 1024; tj27.dst[j27] = guT + (long)e * 2048 * 1024; j27++;
    tj27.src[j27] = euw + (long)e * 1024 * 1024; tj27.dst[j27] = guT + (long)e * 2048 * 1024 + 1024l * 1024; j27++;
    tj27.src[j27] = edw + (long)e * 1024 * 1024; tj27.dst[j27] = dnT + (long)e * 1024 * 1024; j27++;
  }
  tj27.src[j27] = sgw; tj27.dst[j27] = guT + 8l * 2048 * 1024; j27++;
  tj27.src[j27] = suw; tj27.dst[j27] = guT + 8l * 2048 * 1024 + 1024l * 1024; j27++;
  tj27.src[j27] = sdw; tj27.dst[j27] = dnT + 8l * 1024 * 1024; j27++;

  // attention path (rope fused into QKV epilogue)
  rms_trans_kernel<<<2048 + pre, 256, 0, stream>>>(hidden, ln1w, xln1, tj4);
  gemm_kernel<0, 2, 1><<<dim3(24, 16, 1), 256, 0, stream>>>(xln1, wqkvT, qkv, nullptr, nullptr, nullptr, nullptr, pos_ids, 1536, 1024, 0);
  vtrans_kernel<<<dim3(8, 16, 1), 256, 0, stream>>>(qkv, vT);
  attn_trans_kernel<<<512 + 27 * 128, 256, 0, stream>>>(qkv, vT, attnO, tj27);
  // WO: K-split x2 into f32 partials; rms2r combines into OUT(resid) + x2 + router
  gemm_kernel<2, 2, 0><<<dim3(16, 16, 2), 256, 0, stream>>>(attnO, woT, wo_part, nullptr, nullptr, nullptr, nullptr, nullptr, 1024, 1024, 2048l * 1024);
  rms2r_kernel<<<2048, 256, 0, stream>>>(hidden, wo_part, wo_part + 2048l * 1024, ln2w, router_w, segw, out, x2, topi, topw, probs, pwts + 4096);

  // MoE path (shared expert = segment 8; its pw = sgate from router)
  compact_kernel<<<1, 256, 0, stream>>>(topi, topw, segc, sego, ptok, pwts, probs, out + 2097152, tslot);

  // flattened worklists: y = m-tile index (0..15 shared-first, 16..55 routed)
  gemm_kernel<5, 4, 0><<<dim3(16, 56, 1), 256, 0, stream>>>(x2, guT, act_all, ptok, nullptr, segc, sego, nullptr, 1024, 1024, 2048l * 1024);
  gemm_kernel<7, 2, 0><<<dim3(16, 56, 1), 256, 0, stream>>>(act_all, dnT, y_all, ptok, nullptr, segc, sego, nullptr, 1024, 1024, 1024l * 1024);
  combine_kernel<<<2048, 256, 0, stream>>>(y_all, tslot, pwts, out);
}